// Round 1
// baseline (3078.464 us; speedup 1.0000x reference)
//
#include <hip/hip_runtime.h>
#include <stdint.h>

typedef __attribute__((ext_vector_type(4))) float f32x4;
typedef __attribute__((ext_vector_type(8))) short bf16x8;

#define HIDC 256
#define MSGC 128
#define NLAYER 10

__device__ __forceinline__ ushort f2bf(float f) {
  union { float f; uint32_t u; } a; a.f = f;
  uint32_t u = a.u;
  return (ushort)((u + 0x7fffu + ((u >> 16) & 1u)) >> 16);
}
__device__ __forceinline__ float bf2f(ushort h) {
  union { float f; uint32_t u; } a; a.u = ((uint32_t)h) << 16;
  return a.f;
}

// ---------------------------------------------------------------------------
// GEMM: C[M x Nn] = act(A[M x K](f32) @ (Bh+Bl)[Nn x K]^T(bf16 hi/lo) + bias)
// B stored transposed [N][K] so fragments are contiguous-K 16B loads.
// Tile 128x128, BK=64, 4 waves (2x2), hi/lo split -> 3 MFMAs per frag pair.
// ---------------------------------------------------------------------------
template <int RELU>
__global__ __launch_bounds__(256, 2) void gemm_hilo(
    const float* __restrict__ A, const ushort* __restrict__ Bh,
    const ushort* __restrict__ Bl, const float* __restrict__ bias,
    float* __restrict__ C, int M, int K, int Nn) {
  __shared__ ushort lAh[128 * 64];
  __shared__ ushort lAl[128 * 64];
  __shared__ ushort lBh[128 * 64];
  __shared__ ushort lBl[128 * 64];
  const int tid = threadIdx.x;
  const int m0 = blockIdx.x * 128;
  const int n0 = blockIdx.y * 128;
  const int lane = tid & 63;
  const int w = tid >> 6;
  const int wm = (w >> 1) * 64;
  const int wn = (w & 1) * 64;
  const int rr = tid >> 3;  // 0..31 (staging row within pass)
  const int cc = tid & 7;   // 0..7  (16B chunk within 128B LDS row)
  f32x4 acc[4][4] = {};

  const int nsteps = K >> 6;
  for (int s = 0; s < nsteps; ++s) {
    const int k0 = s * 64;
    // ---- stage A (128 rows x 64 f32 -> hi/lo bf16), 4 passes of 32 rows
#pragma unroll
    for (int p = 0; p < 4; ++p) {
      const int row = p * 32 + rr;
      const int gm = m0 + row;
      f32x4 va = {0.f, 0.f, 0.f, 0.f}, vb = {0.f, 0.f, 0.f, 0.f};
      if (gm < M) {
        const float* ga = A + (size_t)gm * K + k0 + cc * 8;
        va = *(const f32x4*)ga;
        vb = *(const f32x4*)(ga + 4);
      }
      bf16x8 hv, lv;
#pragma unroll
      for (int e = 0; e < 4; ++e) {
        float v = va[e];
        ushort hh = f2bf(v);
        hv[e] = (short)hh;
        lv[e] = (short)f2bf(v - bf2f(hh));
        float v2 = vb[e];
        ushort hh2 = f2bf(v2);
        hv[e + 4] = (short)hh2;
        lv[e + 4] = (short)f2bf(v2 - bf2f(hh2));
      }
      const uint32_t off = (uint32_t)((row * 128 + cc * 16) ^ ((row & 7) << 4));
      *(bf16x8*)((char*)lAh + off) = hv;
      *(bf16x8*)((char*)lAl + off) = lv;
    }
    // ---- stage B (128 n-rows x 64 k bf16, already hi/lo)
#pragma unroll
    for (int p = 0; p < 4; ++p) {
      const int row = p * 32 + rr;
      const size_t gb = (size_t)(n0 + row) * K + k0 + cc * 8;
      bf16x8 bh = *(const bf16x8*)(Bh + gb);
      bf16x8 bl = *(const bf16x8*)(Bl + gb);
      const uint32_t off = (uint32_t)((row * 128 + cc * 16) ^ ((row & 7) << 4));
      *(bf16x8*)((char*)lBh + off) = bh;
      *(bf16x8*)((char*)lBl + off) = bl;
    }
    __syncthreads();
    // ---- compute: 2 k-substeps of 32
#pragma unroll
    for (int kk = 0; kk < 2; ++kk) {
      bf16x8 ah[4], al[4], bh[4], bl[4];
#pragma unroll
      for (int i = 0; i < 4; ++i) {
        const int arow = wm + i * 16 + (lane & 15);
        const uint32_t ao =
            (uint32_t)((arow * 128 + kk * 64 + ((lane >> 4) * 16)) ^ ((arow & 7) << 4));
        ah[i] = *(const bf16x8*)((const char*)lAh + ao);
        al[i] = *(const bf16x8*)((const char*)lAl + ao);
        const int brow = wn + i * 16 + (lane & 15);
        const uint32_t bo =
            (uint32_t)((brow * 128 + kk * 64 + ((lane >> 4) * 16)) ^ ((brow & 7) << 4));
        bh[i] = *(const bf16x8*)((const char*)lBh + bo);
        bl[i] = *(const bf16x8*)((const char*)lBl + bo);
      }
#pragma unroll
      for (int i = 0; i < 4; ++i)
#pragma unroll
        for (int j = 0; j < 4; ++j) {
          acc[i][j] = __builtin_amdgcn_mfma_f32_16x16x32_bf16(ah[i], bh[j], acc[i][j], 0, 0, 0);
          acc[i][j] = __builtin_amdgcn_mfma_f32_16x16x32_bf16(ah[i], bl[j], acc[i][j], 0, 0, 0);
          acc[i][j] = __builtin_amdgcn_mfma_f32_16x16x32_bf16(al[i], bh[j], acc[i][j], 0, 0, 0);
        }
    }
    __syncthreads();
  }
  // ---- epilogue: D row = (lane>>4)*4 + r, col = lane&15 (per 16x16 frag)
  float bi[4];
#pragma unroll
  for (int j = 0; j < 4; ++j) bi[j] = bias[n0 + wn + j * 16 + (lane & 15)];
#pragma unroll
  for (int i = 0; i < 4; ++i) {
    const int gm0 = m0 + wm + i * 16 + ((lane >> 4) << 2);
#pragma unroll
    for (int r = 0; r < 4; ++r) {
      const int gm = gm0 + r;
      if (gm < M) {
        const size_t base = (size_t)gm * Nn + n0 + wn + (lane & 15);
#pragma unroll
        for (int j = 0; j < 4; ++j) {
          float v = acc[i][j][r] + bi[j];
          if (RELU) v = fmaxf(v, 0.f);
          C[base + j * 16] = v;
        }
      }
    }
  }
}

// ---------------------------------------------------------------------------
// CSR build
// ---------------------------------------------------------------------------
__global__ void count_kernel(const int* __restrict__ dstv, int* __restrict__ deg, int E) {
  int i = blockIdx.x * 256 + threadIdx.x;
  if (i < E) atomicAdd(&deg[dstv[i]], 1);
}

__global__ __launch_bounds__(1024) void scan_kernel(const int* __restrict__ deg,
                                                    int* __restrict__ rowptr,
                                                    int* __restrict__ fillptr,
                                                    float* __restrict__ invc, int n) {
  __shared__ int smem[1024];
  __shared__ int carry_s;
  if (threadIdx.x == 0) carry_s = 0;
  __syncthreads();
  for (int base = 0; base < n; base += 1024) {
    const int i = base + threadIdx.x;
    const int v = (i < n) ? deg[i] : 0;
    smem[threadIdx.x] = v;
    __syncthreads();
    for (int off = 1; off < 1024; off <<= 1) {
      int t = (threadIdx.x >= off) ? smem[threadIdx.x - off] : 0;
      __syncthreads();
      smem[threadIdx.x] += t;
      __syncthreads();
    }
    const int incl = smem[threadIdx.x];
    const int excl = incl - v;
    const int c = carry_s;
    if (i < n) {
      rowptr[i] = c + excl;
      fillptr[i] = c + excl;
      invc[i] = 1.0f / (float)(v + 1);
    }
    __syncthreads();
    if (threadIdx.x == 0) carry_s = c + smem[1023];
    __syncthreads();
  }
  if (threadIdx.x == 0) rowptr[n] = carry_s;
}

__global__ void fill_kernel(const int* __restrict__ srcv, const int* __restrict__ dstv,
                            int* __restrict__ fillptr, int* __restrict__ colv, int E) {
  int i = blockIdx.x * 256 + threadIdx.x;
  if (i < E) {
    int p = atomicAdd(&fillptr[dstv[i]], 1);
    colv[p] = srcv[i];
  }
}

// ---------------------------------------------------------------------------
// Aggregation: h[v] = z[v] + (A[v] + sum_{e:dst=v} A[src_e]) * invc[v]
// one wave per node, f32x4 per lane (256 cols)
// ---------------------------------------------------------------------------
__global__ __launch_bounds__(256) void agg_kernel(
    const float* __restrict__ z, const float* __restrict__ Am,
    const int* __restrict__ rowptr, const int* __restrict__ colv,
    const float* __restrict__ invc, float* __restrict__ hout, int n) {
  const int node = blockIdx.x * 4 + (threadIdx.x >> 6);
  if (node >= n) return;
  const int lane = threadIdx.x & 63;
  const f32x4* Av = (const f32x4*)Am;
  f32x4 acc = Av[(size_t)node * 64 + lane];
  const int s = rowptr[node];
  const int e = rowptr[node + 1];
  for (int i = s; i < e; ++i) {
    const int src = colv[i];
    acc += Av[(size_t)src * 64 + lane];
  }
  const float ic = invc[node];
  const f32x4 icv = {ic, ic, ic, ic};
  const f32x4 zz = ((const f32x4*)z)[(size_t)node * 64 + lane];
  ((f32x4*)hout)[(size_t)node * 64 + lane] = zz + acc * icv;
}

// ---------------------------------------------------------------------------
// LayerNorm + beta-weighted output accumulation. one wave per row.
// ---------------------------------------------------------------------------
__global__ __launch_bounds__(256) void ln_kernel(
    const float* __restrict__ O, const float* __restrict__ g,
    const float* __restrict__ b, const float* __restrict__ betas, int lidx,
    float* __restrict__ z, float* __restrict__ outp, int n) {
  const int row = blockIdx.x * 4 + (threadIdx.x >> 6);
  if (row >= n) return;
  const int lane = threadIdx.x & 63;
  const f32x4 v = ((const f32x4*)O)[(size_t)row * 64 + lane];
  float s1 = v[0] + v[1] + v[2] + v[3];
  float s2 = v[0] * v[0] + v[1] * v[1] + v[2] * v[2] + v[3] * v[3];
#pragma unroll
  for (int d = 1; d < 64; d <<= 1) {
    s1 += __shfl_xor(s1, d);
    s2 += __shfl_xor(s2, d);
  }
  const float mu = s1 * (1.f / 256.f);
  const float var = s2 * (1.f / 256.f) - mu * mu;
  const float rs = rsqrtf(var + 1e-5f);
  const f32x4 gv = ((const f32x4*)g)[lane];
  const f32x4 bv = ((const f32x4*)b)[lane];
  f32x4 y;
#pragma unroll
  for (int c = 0; c < 4; ++c) y[c] = (v[c] - mu) * rs * gv[c] + bv[c];
  ((f32x4*)z)[(size_t)row * 64 + lane] = y;
  const float be = betas[lidx];
  const f32x4 bev = {be, be, be, be};
  f32x4 o = ((f32x4*)outp)[(size_t)row * 64 + lane];
  ((f32x4*)outp)[(size_t)row * 64 + lane] = o + bev * y;
}

__global__ void scale0_kernel(const float* __restrict__ z, const float* __restrict__ betas,
                              float* __restrict__ outp, int count4) {
  int i = blockIdx.x * 256 + threadIdx.x;
  if (i < count4) {
    const float b0 = betas[0];
    const f32x4 bv = {b0, b0, b0, b0};
    ((f32x4*)outp)[i] = bv * ((const f32x4*)z)[i];
  }
}

__global__ void beta_kernel(const float* __restrict__ beta, float* __restrict__ betas) {
  if (threadIdx.x == 0) {
    float mx = beta[0];
    for (int i = 1; i < NLAYER + 1; ++i) mx = fmaxf(mx, beta[i]);
    float e[NLAYER + 1];
    float s = 0.f;
    for (int i = 0; i < NLAYER + 1; ++i) {
      e[i] = expf(beta[i] - mx);
      s += e[i];
    }
    const float inv = 1.f / s;
    for (int i = 0; i < NLAYER + 1; ++i) betas[i] = e[i] * inv;
  }
}

// W[K][N] f32 -> Wt_hi[N][K], Wt_lo[N][K] bf16 (output-index coalesced)
__global__ void wconv_kernel(const float* __restrict__ W, ushort* __restrict__ Wh,
                             ushort* __restrict__ Wl, int K, int Nn) {
  const size_t matoff = (size_t)blockIdx.z * K * Nn;
  const int o = blockIdx.x * 256 + threadIdx.x;
  if (o >= K * Nn) return;
  const int nn = o / K;
  const int kk = o - nn * K;
  const float v = W[matoff + (size_t)kk * Nn + nn];
  const ushort hh = f2bf(v);
  Wh[matoff + o] = hh;
  Wl[matoff + o] = f2bf(v - bf2f(hh));
}

// ---------------------------------------------------------------------------
extern "C" void kernel_launch(void* const* d_in, const int* in_sizes, int n_in,
                              void* d_out, int out_size, void* d_ws, size_t ws_size,
                              hipStream_t stream) {
  const float* x = (const float*)d_in[0];
  const int* eidx = (const int*)d_in[1];
  const float* Win = (const float*)d_in[2];
  const float* bin_ = (const float*)d_in[3];
  const float* W1 = (const float*)d_in[4];
  const float* b1 = (const float*)d_in[5];
  const float* W2 = (const float*)d_in[6];
  const float* b2 = (const float*)d_in[7];
  const float* U1 = (const float*)d_in[8];
  const float* c1 = (const float*)d_in[9];
  const float* U2 = (const float*)d_in[10];
  const float* c2 = (const float*)d_in[11];
  const float* ln_g = (const float*)d_in[12];
  const float* ln_b = (const float*)d_in[13];
  const float* beta = (const float*)d_in[14];
  float* outp = (float*)d_out;

  const int Nn = in_sizes[0] / 128;  // 50000
  const int E = in_sizes[1] / 2;     // 800000
  const int* srcv = eidx;
  const int* dstv = eidx + E;

  char* p = (char*)d_ws;
  auto alloc = [&](size_t bytes) {
    char* r = p;
    p += (bytes + 255) & ~(size_t)255;
    return r;
  };
  float* z = (float*)alloc((size_t)Nn * HIDC * 4);
  float* hbuf = (float*)alloc((size_t)Nn * HIDC * 4);
  float* T = (float*)alloc((size_t)Nn * HIDC * 4);
  float* P = (float*)alloc((size_t)Nn * HIDC * 4);
  ushort* WinTh = (ushort*)alloc(128 * 256 * 2);
  ushort* WinTl = (ushort*)alloc(128 * 256 * 2);
  ushort* W1Th = (ushort*)alloc((size_t)NLAYER * 256 * 128 * 2);
  ushort* W1Tl = (ushort*)alloc((size_t)NLAYER * 256 * 128 * 2);
  ushort* W2Th = (ushort*)alloc((size_t)NLAYER * 128 * 256 * 2);
  ushort* W2Tl = (ushort*)alloc((size_t)NLAYER * 128 * 256 * 2);
  ushort* U1Th = (ushort*)alloc((size_t)NLAYER * 256 * 256 * 2);
  ushort* U1Tl = (ushort*)alloc((size_t)NLAYER * 256 * 256 * 2);
  ushort* U2Th = (ushort*)alloc((size_t)NLAYER * 256 * 256 * 2);
  ushort* U2Tl = (ushort*)alloc((size_t)NLAYER * 256 * 256 * 2);
  int* deg = (int*)alloc((size_t)Nn * 4);
  int* rowptr = (int*)alloc((size_t)(Nn + 1) * 4);
  int* fillptr = (int*)alloc((size_t)Nn * 4);
  float* invc = (float*)alloc((size_t)Nn * 4);
  int* colv = (int*)alloc((size_t)E * 4);
  float* betas = (float*)alloc(64);

  // CSR build + betas + weight conversion
  hipMemsetAsync(deg, 0, (size_t)Nn * 4, stream);
  count_kernel<<<(E + 255) / 256, 256, 0, stream>>>(dstv, deg, E);
  scan_kernel<<<1, 1024, 0, stream>>>(deg, rowptr, fillptr, invc, Nn);
  fill_kernel<<<(E + 255) / 256, 256, 0, stream>>>(srcv, dstv, fillptr, colv, E);
  beta_kernel<<<1, 64, 0, stream>>>(beta, betas);
  wconv_kernel<<<dim3(128, 1, 1), 256, 0, stream>>>(Win, WinTh, WinTl, 128, 256);
  wconv_kernel<<<dim3(128, 1, NLAYER), 256, 0, stream>>>(W1, W1Th, W1Tl, 256, 128);
  wconv_kernel<<<dim3(128, 1, NLAYER), 256, 0, stream>>>(W2, W2Th, W2Tl, 128, 256);
  wconv_kernel<<<dim3(256, 1, NLAYER), 256, 0, stream>>>(U1, U1Th, U1Tl, 256, 256);
  wconv_kernel<<<dim3(256, 1, NLAYER), 256, 0, stream>>>(U2, U2Th, U2Tl, 256, 256);

  const int mblocks = (Nn + 127) / 128;
  const int nwave = (Nn + 3) / 4;

  // z0 = x @ Win + bin
  gemm_hilo<0><<<dim3(mblocks, 2), 256, 0, stream>>>(x, WinTh, WinTl, bin_, z, Nn, 128, 256);
  scale0_kernel<<<(Nn * 64 + 255) / 256, 256, 0, stream>>>(z, betas, outp, Nn * 64);

  for (int l = 0; l < NLAYER; ++l) {
    // T = relu(z @ W1 + b1)   [N x 128]
    gemm_hilo<1><<<dim3(mblocks, 1), 256, 0, stream>>>(
        z, W1Th + (size_t)l * 256 * 128, W1Tl + (size_t)l * 256 * 128, b1 + l * 128, T,
        Nn, 256, 128);
    // P = T @ W2 + b2         [N x 256]
    gemm_hilo<0><<<dim3(mblocks, 2), 256, 0, stream>>>(
        T, W2Th + (size_t)l * 128 * 256, W2Tl + (size_t)l * 128 * 256, b2 + l * 256, P,
        Nn, 128, 256);
    // h = z + segmean(P)
    agg_kernel<<<nwave, 256, 0, stream>>>(z, P, rowptr, colv, invc, hbuf, Nn);
    // T = relu(h @ U1 + c1)   [N x 256]
    gemm_hilo<1><<<dim3(mblocks, 2), 256, 0, stream>>>(
        hbuf, U1Th + (size_t)l * 256 * 256, U1Tl + (size_t)l * 256 * 256, c1 + l * 256, T,
        Nn, 256, 256);
    // P = T @ U2 + c2         [N x 256]
    gemm_hilo<0><<<dim3(mblocks, 2), 256, 0, stream>>>(
        T, U2Th + (size_t)l * 256 * 256, U2Tl + (size_t)l * 256 * 256, c2 + l * 256, P,
        Nn, 256, 256);
    // z = LN(P)*g+b ; out += betas[l+1]*z
    ln_kernel<<<nwave, 256, 0, stream>>>(P, ln_g + l * 256, ln_b + l * 256, betas, l + 1,
                                         z, outp, Nn);
  }
}

// Round 2
// 2752.957 us; speedup vs baseline: 1.1182x; 1.1182x over previous
//
#include <hip/hip_runtime.h>
#include <stdint.h>

typedef __attribute__((ext_vector_type(4))) float f32x4;
typedef __attribute__((ext_vector_type(2))) float f32x2;
typedef __attribute__((ext_vector_type(8))) short bf16x8;

#define HIDC 256
#define MSGC 128
#define NLAYER 10

__device__ __forceinline__ ushort f2bf(float f) {
  union { float f; uint32_t u; } a; a.f = f;
  uint32_t u = a.u;
  return (ushort)((u + 0x7fffu + ((u >> 16) & 1u)) >> 16);
}
__device__ __forceinline__ float bf2f(ushort h) {
  union { float f; uint32_t u; } a; a.u = ((uint32_t)h) << 16;
  return a.f;
}

// ---------------------------------------------------------------------------
// GEMM: C[M x Nn] = act(A[M x K](f32) @ (Bh+Bl)[Nn x K]^T(bf16 hi/lo) + bias
//                       [+ Z row-wise])
// B stored transposed [N][K] so fragments are contiguous-K 16B loads.
// Tile 128x128, BK=64, 4 waves (2x2), hi/lo split -> 3 MFMAs per frag pair.
// ---------------------------------------------------------------------------
template <int RELU, int ADDZ>
__global__ __launch_bounds__(256, 2) void gemm_hilo(
    const float* __restrict__ A, const ushort* __restrict__ Bh,
    const ushort* __restrict__ Bl, const float* __restrict__ bias,
    const float* __restrict__ Z, float* __restrict__ C, int M, int K, int Nn) {
  __shared__ ushort lAh[128 * 64];
  __shared__ ushort lAl[128 * 64];
  __shared__ ushort lBh[128 * 64];
  __shared__ ushort lBl[128 * 64];
  const int tid = threadIdx.x;
  const int m0 = blockIdx.x * 128;
  const int n0 = blockIdx.y * 128;
  const int lane = tid & 63;
  const int w = tid >> 6;
  const int wm = (w >> 1) * 64;
  const int wn = (w & 1) * 64;
  const int rr = tid >> 3;  // 0..31 (staging row within pass)
  const int cc = tid & 7;   // 0..7  (16B chunk within 128B LDS row)
  f32x4 acc[4][4] = {};

  const int nsteps = K >> 6;
  for (int s = 0; s < nsteps; ++s) {
    const int k0 = s * 64;
    // ---- stage A (128 rows x 64 f32 -> hi/lo bf16), 4 passes of 32 rows
#pragma unroll
    for (int p = 0; p < 4; ++p) {
      const int row = p * 32 + rr;
      const int gm = m0 + row;
      f32x4 va = {0.f, 0.f, 0.f, 0.f}, vb = {0.f, 0.f, 0.f, 0.f};
      if (gm < M) {
        const float* ga = A + (size_t)gm * K + k0 + cc * 8;
        va = *(const f32x4*)ga;
        vb = *(const f32x4*)(ga + 4);
      }
      bf16x8 hv, lv;
#pragma unroll
      for (int e = 0; e < 4; ++e) {
        float v = va[e];
        ushort hh = f2bf(v);
        hv[e] = (short)hh;
        lv[e] = (short)f2bf(v - bf2f(hh));
        float v2 = vb[e];
        ushort hh2 = f2bf(v2);
        hv[e + 4] = (short)hh2;
        lv[e + 4] = (short)f2bf(v2 - bf2f(hh2));
      }
      const uint32_t off = (uint32_t)((row * 128 + cc * 16) ^ ((row & 7) << 4));
      *(bf16x8*)((char*)lAh + off) = hv;
      *(bf16x8*)((char*)lAl + off) = lv;
    }
    // ---- stage B (128 n-rows x 64 k bf16, already hi/lo)
#pragma unroll
    for (int p = 0; p < 4; ++p) {
      const int row = p * 32 + rr;
      const size_t gb = (size_t)(n0 + row) * K + k0 + cc * 8;
      bf16x8 bh = *(const bf16x8*)(Bh + gb);
      bf16x8 bl = *(const bf16x8*)(Bl + gb);
      const uint32_t off = (uint32_t)((row * 128 + cc * 16) ^ ((row & 7) << 4));
      *(bf16x8*)((char*)lBh + off) = bh;
      *(bf16x8*)((char*)lBl + off) = bl;
    }
    __syncthreads();
    // ---- compute: 2 k-substeps of 32
#pragma unroll
    for (int kk = 0; kk < 2; ++kk) {
      bf16x8 ah[4], al[4], bh[4], bl[4];
#pragma unroll
      for (int i = 0; i < 4; ++i) {
        const int arow = wm + i * 16 + (lane & 15);
        const uint32_t ao =
            (uint32_t)((arow * 128 + kk * 64 + ((lane >> 4) * 16)) ^ ((arow & 7) << 4));
        ah[i] = *(const bf16x8*)((const char*)lAh + ao);
        al[i] = *(const bf16x8*)((const char*)lAl + ao);
        const int brow = wn + i * 16 + (lane & 15);
        const uint32_t bo =
            (uint32_t)((brow * 128 + kk * 64 + ((lane >> 4) * 16)) ^ ((brow & 7) << 4));
        bh[i] = *(const bf16x8*)((const char*)lBh + bo);
        bl[i] = *(const bf16x8*)((const char*)lBl + bo);
      }
#pragma unroll
      for (int i = 0; i < 4; ++i)
#pragma unroll
        for (int j = 0; j < 4; ++j) {
          acc[i][j] = __builtin_amdgcn_mfma_f32_16x16x32_bf16(ah[i], bh[j], acc[i][j], 0, 0, 0);
          acc[i][j] = __builtin_amdgcn_mfma_f32_16x16x32_bf16(ah[i], bl[j], acc[i][j], 0, 0, 0);
          acc[i][j] = __builtin_amdgcn_mfma_f32_16x16x32_bf16(al[i], bh[j], acc[i][j], 0, 0, 0);
        }
    }
    __syncthreads();
  }
  // ---- epilogue: D row = (lane>>4)*4 + r, col = lane&15 (per 16x16 frag)
  float bi[4];
#pragma unroll
  for (int j = 0; j < 4; ++j) bi[j] = bias[n0 + wn + j * 16 + (lane & 15)];
#pragma unroll
  for (int i = 0; i < 4; ++i) {
    const int gm0 = m0 + wm + i * 16 + ((lane >> 4) << 2);
#pragma unroll
    for (int r = 0; r < 4; ++r) {
      const int gm = gm0 + r;
      if (gm < M) {
        const size_t base = (size_t)gm * Nn + n0 + wn + (lane & 15);
#pragma unroll
        for (int j = 0; j < 4; ++j) {
          float v = acc[i][j][r] + bi[j];
          if (ADDZ) v += Z[base + j * 16];
          if (RELU) v = fmaxf(v, 0.f);
          C[base + j * 16] = v;
        }
      }
    }
  }
}

// ---------------------------------------------------------------------------
// CSR build
// ---------------------------------------------------------------------------
__global__ void count_kernel(const int* __restrict__ dstv, int* __restrict__ deg, int E) {
  int i = blockIdx.x * 256 + threadIdx.x;
  if (i < E) atomicAdd(&deg[dstv[i]], 1);
}

__global__ __launch_bounds__(1024) void scan_kernel(const int* __restrict__ deg,
                                                    int* __restrict__ rowptr,
                                                    int* __restrict__ fillptr,
                                                    float* __restrict__ invc, int n) {
  __shared__ int smem[1024];
  __shared__ int carry_s;
  if (threadIdx.x == 0) carry_s = 0;
  __syncthreads();
  for (int base = 0; base < n; base += 1024) {
    const int i = base + threadIdx.x;
    const int v = (i < n) ? deg[i] : 0;
    smem[threadIdx.x] = v;
    __syncthreads();
    for (int off = 1; off < 1024; off <<= 1) {
      int t = (threadIdx.x >= off) ? smem[threadIdx.x - off] : 0;
      __syncthreads();
      smem[threadIdx.x] += t;
      __syncthreads();
    }
    const int incl = smem[threadIdx.x];
    const int excl = incl - v;
    const int c = carry_s;
    if (i < n) {
      rowptr[i] = c + excl;
      fillptr[i] = c + excl;
      invc[i] = 1.0f / (float)(v + 1);
    }
    __syncthreads();
    if (threadIdx.x == 0) carry_s = c + smem[1023];
    __syncthreads();
  }
  if (threadIdx.x == 0) rowptr[n] = carry_s;
}

__global__ void fill_kernel(const int* __restrict__ srcv, const int* __restrict__ dstv,
                            int* __restrict__ fillptr, int* __restrict__ colv, int E) {
  int i = blockIdx.x * 256 + threadIdx.x;
  if (i < E) {
    int p = atomicAdd(&fillptr[dstv[i]], 1);
    colv[p] = srcv[i];
  }
}

// ---------------------------------------------------------------------------
// 128-d aggregation: s[v] = (T[v] + sum_{e:dst=v} T[src_e]) * invc[v]
// one wave per node, f32x2 per lane (128 cols)
// ---------------------------------------------------------------------------
__global__ __launch_bounds__(256) void agg128_kernel(
    const float* __restrict__ T, const int* __restrict__ rowptr,
    const int* __restrict__ colv, const float* __restrict__ invc,
    float* __restrict__ sout, int n) {
  const int node = blockIdx.x * 4 + (threadIdx.x >> 6);
  if (node >= n) return;
  const int lane = threadIdx.x & 63;
  const f32x2* Tv = (const f32x2*)T;
  f32x2 acc = Tv[(size_t)node * 64 + lane];
  const int s = rowptr[node];
  const int e = rowptr[node + 1];
  for (int i = s; i < e; ++i) {
    const int src = colv[i];
    acc += Tv[(size_t)src * 64 + lane];
  }
  const float ic = invc[node];
  f32x2 r;
  r[0] = acc[0] * ic;
  r[1] = acc[1] * ic;
  ((f32x2*)sout)[(size_t)node * 64 + lane] = r;
}

// ---------------------------------------------------------------------------
// LayerNorm + beta-weighted output accumulation. one wave per row.
// ---------------------------------------------------------------------------
__global__ __launch_bounds__(256) void ln_kernel(
    const float* __restrict__ O, const float* __restrict__ g,
    const float* __restrict__ b, const float* __restrict__ betas, int lidx,
    float* __restrict__ z, float* __restrict__ outp, int n) {
  const int row = blockIdx.x * 4 + (threadIdx.x >> 6);
  if (row >= n) return;
  const int lane = threadIdx.x & 63;
  const f32x4 v = ((const f32x4*)O)[(size_t)row * 64 + lane];
  float s1 = v[0] + v[1] + v[2] + v[3];
  float s2 = v[0] * v[0] + v[1] * v[1] + v[2] * v[2] + v[3] * v[3];
#pragma unroll
  for (int d = 1; d < 64; d <<= 1) {
    s1 += __shfl_xor(s1, d);
    s2 += __shfl_xor(s2, d);
  }
  const float mu = s1 * (1.f / 256.f);
  const float var = s2 * (1.f / 256.f) - mu * mu;
  const float rs = rsqrtf(var + 1e-5f);
  const f32x4 gv = ((const f32x4*)g)[lane];
  const f32x4 bv = ((const f32x4*)b)[lane];
  f32x4 y;
#pragma unroll
  for (int c = 0; c < 4; ++c) y[c] = (v[c] - mu) * rs * gv[c] + bv[c];
  ((f32x4*)z)[(size_t)row * 64 + lane] = y;
  const float be = betas[lidx];
  const f32x4 bev = {be, be, be, be};
  f32x4 o = ((f32x4*)outp)[(size_t)row * 64 + lane];
  ((f32x4*)outp)[(size_t)row * 64 + lane] = o + bev * y;
}

__global__ void scale0_kernel(const float* __restrict__ z, const float* __restrict__ betas,
                              float* __restrict__ outp, int count4) {
  int i = blockIdx.x * 256 + threadIdx.x;
  if (i < count4) {
    const float b0 = betas[0];
    const f32x4 bv = {b0, b0, b0, b0};
    ((f32x4*)outp)[i] = bv * ((const f32x4*)z)[i];
  }
}

__global__ void beta_kernel(const float* __restrict__ beta, float* __restrict__ betas) {
  if (threadIdx.x == 0) {
    float mx = beta[0];
    for (int i = 1; i < NLAYER + 1; ++i) mx = fmaxf(mx, beta[i]);
    float e[NLAYER + 1];
    float s = 0.f;
    for (int i = 0; i < NLAYER + 1; ++i) {
      e[i] = expf(beta[i] - mx);
      s += e[i];
    }
    const float inv = 1.f / s;
    for (int i = 0; i < NLAYER + 1; ++i) betas[i] = e[i] * inv;
  }
}

// W[K][N] f32 -> Wt_hi[N][K], Wt_lo[N][K] bf16 (output-index coalesced)
__global__ void wconv_kernel(const float* __restrict__ W, ushort* __restrict__ Wh,
                             ushort* __restrict__ Wl, int K, int Nn) {
  const size_t matoff = (size_t)blockIdx.z * K * Nn;
  const int o = blockIdx.x * 256 + threadIdx.x;
  if (o >= K * Nn) return;
  const int nn = o / K;
  const int kk = o - nn * K;
  const float v = W[matoff + (size_t)kk * Nn + nn];
  const ushort hh = f2bf(v);
  Wh[matoff + o] = hh;
  Wl[matoff + o] = f2bf(v - bf2f(hh));
}

// ---------------------------------------------------------------------------
extern "C" void kernel_launch(void* const* d_in, const int* in_sizes, int n_in,
                              void* d_out, int out_size, void* d_ws, size_t ws_size,
                              hipStream_t stream) {
  const float* x = (const float*)d_in[0];
  const int* eidx = (const int*)d_in[1];
  const float* Win = (const float*)d_in[2];
  const float* bin_ = (const float*)d_in[3];
  const float* W1 = (const float*)d_in[4];
  const float* b1 = (const float*)d_in[5];
  const float* W2 = (const float*)d_in[6];
  const float* b2 = (const float*)d_in[7];
  const float* U1 = (const float*)d_in[8];
  const float* c1 = (const float*)d_in[9];
  const float* U2 = (const float*)d_in[10];
  const float* c2 = (const float*)d_in[11];
  const float* ln_g = (const float*)d_in[12];
  const float* ln_b = (const float*)d_in[13];
  const float* beta = (const float*)d_in[14];
  float* outp = (float*)d_out;

  const int Nn = in_sizes[0] / 128;  // 50000
  const int E = in_sizes[1] / 2;     // 800000
  const int* srcv = eidx;
  const int* dstv = eidx + E;

  char* p = (char*)d_ws;
  auto alloc = [&](size_t bytes) {
    char* r = p;
    p += (bytes + 255) & ~(size_t)255;
    return r;
  };
  float* z = (float*)alloc((size_t)Nn * HIDC * 4);
  float* hbuf = (float*)alloc((size_t)Nn * HIDC * 4);
  float* R = (float*)alloc((size_t)Nn * HIDC * 4);  // T128 | s128, also O256
  float* P = (float*)alloc((size_t)Nn * HIDC * 4);
  ushort* WinTh = (ushort*)alloc(128 * 256 * 2);
  ushort* WinTl = (ushort*)alloc(128 * 256 * 2);
  ushort* W1Th = (ushort*)alloc((size_t)NLAYER * 256 * 128 * 2);
  ushort* W1Tl = (ushort*)alloc((size_t)NLAYER * 256 * 128 * 2);
  ushort* W2Th = (ushort*)alloc((size_t)NLAYER * 128 * 256 * 2);
  ushort* W2Tl = (ushort*)alloc((size_t)NLAYER * 128 * 256 * 2);
  ushort* U1Th = (ushort*)alloc((size_t)NLAYER * 256 * 256 * 2);
  ushort* U1Tl = (ushort*)alloc((size_t)NLAYER * 256 * 256 * 2);
  ushort* U2Th = (ushort*)alloc((size_t)NLAYER * 256 * 256 * 2);
  ushort* U2Tl = (ushort*)alloc((size_t)NLAYER * 256 * 256 * 2);
  int* deg = (int*)alloc((size_t)Nn * 4);
  int* rowptr = (int*)alloc((size_t)(Nn + 1) * 4);
  int* fillptr = (int*)alloc((size_t)Nn * 4);
  float* invc = (float*)alloc((size_t)Nn * 4);
  int* colv = (int*)alloc((size_t)E * 4);
  float* betas = (float*)alloc(64);

  float* T128 = R;                       // [Nn x 128]
  float* s128 = R + (size_t)Nn * MSGC;   // [Nn x 128]
  float* Obuf = R;                       // [Nn x 256] (reuses T128+s128 region)

  // CSR build + betas + weight conversion
  hipMemsetAsync(deg, 0, (size_t)Nn * 4, stream);
  count_kernel<<<(E + 255) / 256, 256, 0, stream>>>(dstv, deg, E);
  scan_kernel<<<1, 1024, 0, stream>>>(deg, rowptr, fillptr, invc, Nn);
  fill_kernel<<<(E + 255) / 256, 256, 0, stream>>>(srcv, dstv, fillptr, colv, E);
  beta_kernel<<<1, 64, 0, stream>>>(beta, betas);
  wconv_kernel<<<dim3(128, 1, 1), 256, 0, stream>>>(Win, WinTh, WinTl, 128, 256);
  wconv_kernel<<<dim3(128, 1, NLAYER), 256, 0, stream>>>(W1, W1Th, W1Tl, 256, 128);
  wconv_kernel<<<dim3(128, 1, NLAYER), 256, 0, stream>>>(W2, W2Th, W2Tl, 128, 256);
  wconv_kernel<<<dim3(256, 1, NLAYER), 256, 0, stream>>>(U1, U1Th, U1Tl, 256, 256);
  wconv_kernel<<<dim3(256, 1, NLAYER), 256, 0, stream>>>(U2, U2Th, U2Tl, 256, 256);

  const int mblocks = (Nn + 127) / 128;
  const int nwave = (Nn + 3) / 4;

  // z0 = x @ Win + bin
  gemm_hilo<0, 0><<<dim3(mblocks, 2), 256, 0, stream>>>(x, WinTh, WinTl, bin_, nullptr,
                                                        z, Nn, 128, 256);
  scale0_kernel<<<(Nn * 64 + 255) / 256, 256, 0, stream>>>(z, betas, outp, Nn * 64);

  for (int l = 0; l < NLAYER; ++l) {
    // T128 = relu(z @ W1 + b1)   [N x 128]
    gemm_hilo<1, 0><<<dim3(mblocks, 1), 256, 0, stream>>>(
        z, W1Th + (size_t)l * 256 * 128, W1Tl + (size_t)l * 256 * 128, b1 + l * 128,
        nullptr, T128, Nn, 256, 128);
    // s128 = segmean(T128)  (128-d aggregation, includes self loop)
    agg128_kernel<<<nwave, 256, 0, stream>>>(T128, rowptr, colv, invc, s128, Nn);
    // h = z + s128 @ W2 + b2     [N x 256]
    gemm_hilo<0, 1><<<dim3(mblocks, 2), 256, 0, stream>>>(
        s128, W2Th + (size_t)l * 128 * 256, W2Tl + (size_t)l * 128 * 256, b2 + l * 256,
        z, hbuf, Nn, 128, 256);
    // O = relu(h @ U1 + c1)      [N x 256]
    gemm_hilo<1, 0><<<dim3(mblocks, 2), 256, 0, stream>>>(
        hbuf, U1Th + (size_t)l * 256 * 256, U1Tl + (size_t)l * 256 * 256, c1 + l * 256,
        nullptr, Obuf, Nn, 256, 256);
    // P = O @ U2 + c2            [N x 256]
    gemm_hilo<0, 0><<<dim3(mblocks, 2), 256, 0, stream>>>(
        Obuf, U2Th + (size_t)l * 256 * 256, U2Tl + (size_t)l * 256 * 256, c2 + l * 256,
        nullptr, P, Nn, 256, 256);
    // z = LN(P)*g+b ; out += betas[l+1]*z
    ln_kernel<<<nwave, 256, 0, stream>>>(P, ln_g + l * 256, ln_b + l * 256, betas, l + 1,
                                         z, outp, Nn);
  }
}

// Round 3
// 2351.389 us; speedup vs baseline: 1.3092x; 1.1708x over previous
//
#include <hip/hip_runtime.h>
#include <stdint.h>

typedef __attribute__((ext_vector_type(4))) float f32x4;
typedef __attribute__((ext_vector_type(2))) float f32x2;
typedef __attribute__((ext_vector_type(8))) short bf16x8;

#define HIDC 256
#define MSGC 128
#define NLAYER 10

__device__ __forceinline__ ushort f2bf(float f) {
  union { float f; uint32_t u; } a; a.f = f;
  uint32_t u = a.u;
  return (ushort)((u + 0x7fffu + ((u >> 16) & 1u)) >> 16);
}
__device__ __forceinline__ float bf2f(ushort h) {
  union { float f; uint32_t u; } a; a.u = ((uint32_t)h) << 16;
  return a.f;
}

// ---------------------------------------------------------------------------
// Small GEMM (kept for W1, N=128): tile 128x128, 4 waves, BK=64.
// ---------------------------------------------------------------------------
template <int RELU>
__global__ __launch_bounds__(256, 2) void gemm_hilo(
    const float* __restrict__ A, const ushort* __restrict__ Bh,
    const ushort* __restrict__ Bl, const float* __restrict__ bias,
    float* __restrict__ C, int M, int K, int Nn) {
  __shared__ ushort lAh[128 * 64];
  __shared__ ushort lAl[128 * 64];
  __shared__ ushort lBh[128 * 64];
  __shared__ ushort lBl[128 * 64];
  const int tid = threadIdx.x;
  const int m0 = blockIdx.x * 128;
  const int n0 = blockIdx.y * 128;
  const int lane = tid & 63;
  const int w = tid >> 6;
  const int wm = (w >> 1) * 64;
  const int wn = (w & 1) * 64;
  const int rr = tid >> 3;
  const int cc = tid & 7;
  f32x4 acc[4][4] = {};

  const int nsteps = K >> 6;
  for (int s = 0; s < nsteps; ++s) {
    const int k0 = s * 64;
#pragma unroll
    for (int p = 0; p < 4; ++p) {
      const int row = p * 32 + rr;
      const int gm = m0 + row;
      f32x4 va = {0.f, 0.f, 0.f, 0.f}, vb = {0.f, 0.f, 0.f, 0.f};
      if (gm < M) {
        const float* ga = A + (size_t)gm * K + k0 + cc * 8;
        va = *(const f32x4*)ga;
        vb = *(const f32x4*)(ga + 4);
      }
      bf16x8 hv, lv;
#pragma unroll
      for (int e = 0; e < 4; ++e) {
        float v = va[e];
        ushort hh = f2bf(v);
        hv[e] = (short)hh;
        lv[e] = (short)f2bf(v - bf2f(hh));
        float v2 = vb[e];
        ushort hh2 = f2bf(v2);
        hv[e + 4] = (short)hh2;
        lv[e + 4] = (short)f2bf(v2 - bf2f(hh2));
      }
      const uint32_t off = (uint32_t)((row * 128 + cc * 16) ^ ((row & 7) << 4));
      *(bf16x8*)((char*)lAh + off) = hv;
      *(bf16x8*)((char*)lAl + off) = lv;
    }
#pragma unroll
    for (int p = 0; p < 4; ++p) {
      const int row = p * 32 + rr;
      const size_t gb = (size_t)(n0 + row) * K + k0 + cc * 8;
      bf16x8 bh = *(const bf16x8*)(Bh + gb);
      bf16x8 bl = *(const bf16x8*)(Bl + gb);
      const uint32_t off = (uint32_t)((row * 128 + cc * 16) ^ ((row & 7) << 4));
      *(bf16x8*)((char*)lBh + off) = bh;
      *(bf16x8*)((char*)lBl + off) = bl;
    }
    __syncthreads();
#pragma unroll
    for (int kk = 0; kk < 2; ++kk) {
      bf16x8 ah[4], al[4], bh[4], bl[4];
#pragma unroll
      for (int i = 0; i < 4; ++i) {
        const int arow = wm + i * 16 + (lane & 15);
        const uint32_t ao =
            (uint32_t)((arow * 128 + kk * 64 + ((lane >> 4) * 16)) ^ ((arow & 7) << 4));
        ah[i] = *(const bf16x8*)((const char*)lAh + ao);
        al[i] = *(const bf16x8*)((const char*)lAl + ao);
        const int brow = wn + i * 16 + (lane & 15);
        const uint32_t bo =
            (uint32_t)((brow * 128 + kk * 64 + ((lane >> 4) * 16)) ^ ((brow & 7) << 4));
        bh[i] = *(const bf16x8*)((const char*)lBh + bo);
        bl[i] = *(const bf16x8*)((const char*)lBl + bo);
      }
#pragma unroll
      for (int i = 0; i < 4; ++i)
#pragma unroll
        for (int j = 0; j < 4; ++j) {
          acc[i][j] = __builtin_amdgcn_mfma_f32_16x16x32_bf16(ah[i], bh[j], acc[i][j], 0, 0, 0);
          acc[i][j] = __builtin_amdgcn_mfma_f32_16x16x32_bf16(ah[i], bl[j], acc[i][j], 0, 0, 0);
          acc[i][j] = __builtin_amdgcn_mfma_f32_16x16x32_bf16(al[i], bh[j], acc[i][j], 0, 0, 0);
        }
    }
    __syncthreads();
  }
  float bi[4];
#pragma unroll
  for (int j = 0; j < 4; ++j) bi[j] = bias[n0 + wn + j * 16 + (lane & 15)];
#pragma unroll
  for (int i = 0; i < 4; ++i) {
    const int gm0 = m0 + wm + i * 16 + ((lane >> 4) << 2);
#pragma unroll
    for (int r = 0; r < 4; ++r) {
      const int gm = gm0 + r;
      if (gm < M) {
        const size_t base = (size_t)gm * Nn + n0 + wn + (lane & 15);
#pragma unroll
        for (int j = 0; j < 4; ++j) {
          float v = acc[i][j][r] + bi[j];
          if (RELU) v = fmaxf(v, 0.f);
          C[base + j * 16] = v;
        }
      }
    }
  }
}

// ---------------------------------------------------------------------------
// Big GEMM: tile 256x256, 8 waves (512 thr), BK=64, N fixed = 256.
// MODE 0: C = act(A@B^T + bias [+Z])
// MODE 1: y = LN(A@B^T + bias)*g + b_; C = y; outp += betas[lidx]*y
// MODE 2: C = A@B^T + bias; outp = betas[lidx]*C   (z0 path)
// ---------------------------------------------------------------------------
template <int RELU, int ADDZ, int MODE>
__global__ __launch_bounds__(512, 2) void gemm_big(
    const float* __restrict__ A, const ushort* __restrict__ Bh,
    const ushort* __restrict__ Bl, const float* __restrict__ bias,
    const float* __restrict__ Z, float* __restrict__ C,
    const float* __restrict__ g, const float* __restrict__ b_,
    const float* __restrict__ betas, int lidx, float* __restrict__ outp,
    int M, int K) {
  __shared__ ushort lAh[256 * 64];
  __shared__ ushort lAl[256 * 64];
  __shared__ ushort lBh[256 * 64];
  __shared__ ushort lBl[256 * 64];
  __shared__ float sstat[2][2][256];  // [s1/s2][col-half][row]
  const int tid = threadIdx.x;
  const int m0 = blockIdx.x * 256;
  const int lane = tid & 63;
  const int w = tid >> 6;          // 0..7
  const int wm = (w >> 1) * 64;    // 0,64,128,192
  const int wn = (w & 1) * 128;    // 0,128
  const int rr = tid >> 3;         // 0..63
  const int cc = tid & 7;          // 0..7
  f32x4 acc[4][8] = {};

  const int nsteps = K >> 6;
  for (int s = 0; s < nsteps; ++s) {
    const int k0 = s * 64;
    // stage A: 256 rows x 64 f32 -> hi/lo, 4 passes of 64 rows
#pragma unroll
    for (int p = 0; p < 4; ++p) {
      const int row = p * 64 + rr;
      const int gm = m0 + row;
      f32x4 va = {0.f, 0.f, 0.f, 0.f}, vb = {0.f, 0.f, 0.f, 0.f};
      if (gm < M) {
        const float* ga = A + (size_t)gm * K + k0 + cc * 8;
        va = *(const f32x4*)ga;
        vb = *(const f32x4*)(ga + 4);
      }
      bf16x8 hv, lv;
#pragma unroll
      for (int e = 0; e < 4; ++e) {
        float v = va[e];
        ushort hh = f2bf(v);
        hv[e] = (short)hh;
        lv[e] = (short)f2bf(v - bf2f(hh));
        float v2 = vb[e];
        ushort hh2 = f2bf(v2);
        hv[e + 4] = (short)hh2;
        lv[e + 4] = (short)f2bf(v2 - bf2f(hh2));
      }
      const uint32_t off = (uint32_t)((row * 128 + cc * 16) ^ ((row & 7) << 4));
      *(bf16x8*)((char*)lAh + off) = hv;
      *(bf16x8*)((char*)lAl + off) = lv;
    }
    // stage B: 256 rows x 64 bf16 hi/lo, 4 passes of 64 rows
#pragma unroll
    for (int p = 0; p < 4; ++p) {
      const int row = p * 64 + rr;
      const size_t gb = (size_t)row * K + k0 + cc * 8;
      bf16x8 bh = *(const bf16x8*)(Bh + gb);
      bf16x8 bl = *(const bf16x8*)(Bl + gb);
      const uint32_t off = (uint32_t)((row * 128 + cc * 16) ^ ((row & 7) << 4));
      *(bf16x8*)((char*)lBh + off) = bh;
      *(bf16x8*)((char*)lBl + off) = bl;
    }
    __syncthreads();
#pragma unroll
    for (int kk = 0; kk < 2; ++kk) {
      bf16x8 ah[4], al[4];
#pragma unroll
      for (int i = 0; i < 4; ++i) {
        const int arow = wm + i * 16 + (lane & 15);
        const uint32_t ao =
            (uint32_t)((arow * 128 + kk * 64 + ((lane >> 4) * 16)) ^ ((arow & 7) << 4));
        ah[i] = *(const bf16x8*)((const char*)lAh + ao);
        al[i] = *(const bf16x8*)((const char*)lAl + ao);
      }
#pragma unroll
      for (int jc = 0; jc < 2; ++jc) {
        bf16x8 bh[4], bl[4];
#pragma unroll
        for (int jj = 0; jj < 4; ++jj) {
          const int brow = wn + jc * 64 + jj * 16 + (lane & 15);
          const uint32_t bo =
              (uint32_t)((brow * 128 + kk * 64 + ((lane >> 4) * 16)) ^ ((brow & 7) << 4));
          bh[jj] = *(const bf16x8*)((const char*)lBh + bo);
          bl[jj] = *(const bf16x8*)((const char*)lBl + bo);
        }
#pragma unroll
        for (int i = 0; i < 4; ++i)
#pragma unroll
          for (int jj = 0; jj < 4; ++jj) {
            const int j = jc * 4 + jj;
            acc[i][j] = __builtin_amdgcn_mfma_f32_16x16x32_bf16(ah[i], bh[jj], acc[i][j], 0, 0, 0);
            acc[i][j] = __builtin_amdgcn_mfma_f32_16x16x32_bf16(ah[i], bl[jj], acc[i][j], 0, 0, 0);
            acc[i][j] = __builtin_amdgcn_mfma_f32_16x16x32_bf16(al[i], bh[jj], acc[i][j], 0, 0, 0);
          }
      }
    }
    __syncthreads();
  }

  // ---- epilogue
  float bi[8];
#pragma unroll
  for (int j = 0; j < 8; ++j) bi[j] = bias[wn + j * 16 + (lane & 15)];

  if (MODE == 1) {
    float gv[8], bv[8];
#pragma unroll
    for (int j = 0; j < 8; ++j) {
      gv[j] = g[wn + j * 16 + (lane & 15)];
      bv[j] = b_[wn + j * 16 + (lane & 15)];
    }
    const float beta_s = betas[lidx];
    // bias add + per-row partial stats over this wave's 128 cols
#pragma unroll
    for (int i = 0; i < 4; ++i) {
#pragma unroll
      for (int r = 0; r < 4; ++r) {
        float s1 = 0.f, s2 = 0.f;
#pragma unroll
        for (int j = 0; j < 8; ++j) {
          float v = acc[i][j][r] + bi[j];
          acc[i][j][r] = v;
          s1 += v;
          s2 += v * v;
        }
#pragma unroll
        for (int d = 1; d < 16; d <<= 1) {
          s1 += __shfl_xor(s1, d);
          s2 += __shfl_xor(s2, d);
        }
        if ((lane & 15) == 0) {
          const int rl = wm + i * 16 + ((lane >> 4) << 2) + r;
          sstat[0][w & 1][rl] = s1;
          sstat[1][w & 1][rl] = s2;
        }
      }
    }
    __syncthreads();
#pragma unroll
    for (int i = 0; i < 4; ++i) {
#pragma unroll
      for (int r = 0; r < 4; ++r) {
        const int rl = wm + i * 16 + ((lane >> 4) << 2) + r;
        const float s1 = sstat[0][0][rl] + sstat[0][1][rl];
        const float s2 = sstat[1][0][rl] + sstat[1][1][rl];
        const float mu = s1 * (1.f / 256.f);
        const float var = s2 * (1.f / 256.f) - mu * mu;
        const float rs = rsqrtf(var + 1e-5f);
        const int gm = m0 + rl;
        if (gm < M) {
          const size_t base = (size_t)gm * 256 + wn + (lane & 15);
#pragma unroll
          for (int j = 0; j < 8; ++j) {
            const float y = (acc[i][j][r] - mu) * rs * gv[j] + bv[j];
            const size_t o = base + j * 16;
            C[o] = y;
            outp[o] = outp[o] + beta_s * y;
          }
        }
      }
    }
  } else {
    const float beta_s = (MODE == 2) ? betas[lidx] : 0.f;
#pragma unroll
    for (int i = 0; i < 4; ++i) {
      const int gm0 = m0 + wm + i * 16 + ((lane >> 4) << 2);
#pragma unroll
      for (int r = 0; r < 4; ++r) {
        const int gm = gm0 + r;
        if (gm < M) {
          const size_t base = (size_t)gm * 256 + wn + (lane & 15);
#pragma unroll
          for (int j = 0; j < 8; ++j) {
            float v = acc[i][j][r] + bi[j];
            if (ADDZ) v += Z[base + j * 16];
            if (RELU) v = fmaxf(v, 0.f);
            C[base + j * 16] = v;
            if (MODE == 2) outp[base + j * 16] = beta_s * v;
          }
        }
      }
    }
  }
}

// ---------------------------------------------------------------------------
// CSR build (parallel scan)
// ---------------------------------------------------------------------------
__global__ void count_kernel(const int* __restrict__ dstv, int* __restrict__ deg, int E) {
  int i = blockIdx.x * 256 + threadIdx.x;
  if (i < E) atomicAdd(&deg[dstv[i]], 1);
}

__global__ void scanA_kernel(const int* __restrict__ deg, int* __restrict__ excl,
                             int* __restrict__ bsum, int n) {
  __shared__ int sm[256];
  const int i = blockIdx.x * 256 + threadIdx.x;
  const int v = (i < n) ? deg[i] : 0;
  sm[threadIdx.x] = v;
  __syncthreads();
  for (int off = 1; off < 256; off <<= 1) {
    int t = (threadIdx.x >= off) ? sm[threadIdx.x - off] : 0;
    __syncthreads();
    sm[threadIdx.x] += t;
    __syncthreads();
  }
  if (i < n) excl[i] = sm[threadIdx.x] - v;
  if (threadIdx.x == 255) bsum[blockIdx.x] = sm[255];
}

__global__ void scanB_kernel(const int* __restrict__ bsum, int* __restrict__ boff, int nb) {
  __shared__ int sm[256];
  const int v = (threadIdx.x < nb) ? bsum[threadIdx.x] : 0;
  sm[threadIdx.x] = v;
  __syncthreads();
  for (int off = 1; off < 256; off <<= 1) {
    int t = (threadIdx.x >= off) ? sm[threadIdx.x - off] : 0;
    __syncthreads();
    sm[threadIdx.x] += t;
    __syncthreads();
  }
  if (threadIdx.x < nb) boff[threadIdx.x] = sm[threadIdx.x] - v;
}

__global__ void scanC_kernel(const int* __restrict__ deg, const int* __restrict__ excl,
                             const int* __restrict__ boff, int* __restrict__ rowptr,
                             int* __restrict__ fillptr, float* __restrict__ invc,
                             int n, int E) {
  const int i = blockIdx.x * 256 + threadIdx.x;
  if (i < n) {
    const int r = excl[i] + boff[blockIdx.x];
    rowptr[i] = r;
    fillptr[i] = r;
    invc[i] = 1.0f / (float)(deg[i] + 1);
  }
  if (i == 0) rowptr[n] = E;
}

__global__ void fill_kernel(const int* __restrict__ srcv, const int* __restrict__ dstv,
                            int* __restrict__ fillptr, int* __restrict__ colv, int E) {
  int i = blockIdx.x * 256 + threadIdx.x;
  if (i < E) {
    int p = atomicAdd(&fillptr[dstv[i]], 1);
    colv[p] = srcv[i];
  }
}

// ---------------------------------------------------------------------------
// 128-d aggregation: s[v] = (T[v] + sum_{e:dst=v} T[src_e]) * invc[v]
// ---------------------------------------------------------------------------
__global__ __launch_bounds__(256) void agg128_kernel(
    const float* __restrict__ T, const int* __restrict__ rowptr,
    const int* __restrict__ colv, const float* __restrict__ invc,
    float* __restrict__ sout, int n) {
  const int node = blockIdx.x * 4 + (threadIdx.x >> 6);
  if (node >= n) return;
  const int lane = threadIdx.x & 63;
  const f32x2* Tv = (const f32x2*)T;
  f32x2 acc = Tv[(size_t)node * 64 + lane];
  const int s = rowptr[node];
  const int e = rowptr[node + 1];
  for (int i = s; i < e; ++i) {
    const int src = colv[i];
    acc += Tv[(size_t)src * 64 + lane];
  }
  const float ic = invc[node];
  f32x2 r;
  r[0] = acc[0] * ic;
  r[1] = acc[1] * ic;
  ((f32x2*)sout)[(size_t)node * 64 + lane] = r;
}

__global__ void beta_kernel(const float* __restrict__ beta, float* __restrict__ betas) {
  if (threadIdx.x == 0) {
    float mx = beta[0];
    for (int i = 1; i < NLAYER + 1; ++i) mx = fmaxf(mx, beta[i]);
    float e[NLAYER + 1];
    float s = 0.f;
    for (int i = 0; i < NLAYER + 1; ++i) {
      e[i] = expf(beta[i] - mx);
      s += e[i];
    }
    const float inv = 1.f / s;
    for (int i = 0; i < NLAYER + 1; ++i) betas[i] = e[i] * inv;
  }
}

// W[K][N] f32 -> Wt_hi[N][K], Wt_lo[N][K] bf16 (output-index coalesced)
__global__ void wconv_kernel(const float* __restrict__ W, ushort* __restrict__ Wh,
                             ushort* __restrict__ Wl, int K, int Nn) {
  const size_t matoff = (size_t)blockIdx.z * K * Nn;
  const int o = blockIdx.x * 256 + threadIdx.x;
  if (o >= K * Nn) return;
  const int nn = o / K;
  const int kk = o - nn * K;
  const float v = W[matoff + (size_t)kk * Nn + nn];
  const ushort hh = f2bf(v);
  Wh[matoff + o] = hh;
  Wl[matoff + o] = f2bf(v - bf2f(hh));
}

// ---------------------------------------------------------------------------
extern "C" void kernel_launch(void* const* d_in, const int* in_sizes, int n_in,
                              void* d_out, int out_size, void* d_ws, size_t ws_size,
                              hipStream_t stream) {
  const float* x = (const float*)d_in[0];
  const int* eidx = (const int*)d_in[1];
  const float* Win = (const float*)d_in[2];
  const float* bin_ = (const float*)d_in[3];
  const float* W1 = (const float*)d_in[4];
  const float* b1 = (const float*)d_in[5];
  const float* W2 = (const float*)d_in[6];
  const float* b2 = (const float*)d_in[7];
  const float* U1 = (const float*)d_in[8];
  const float* c1 = (const float*)d_in[9];
  const float* U2 = (const float*)d_in[10];
  const float* c2 = (const float*)d_in[11];
  const float* ln_g = (const float*)d_in[12];
  const float* ln_b = (const float*)d_in[13];
  const float* beta = (const float*)d_in[14];
  float* outp = (float*)d_out;

  const int Nn = in_sizes[0] / 128;  // 50000
  const int E = in_sizes[1] / 2;     // 800000
  const int* srcv = eidx;
  const int* dstv = eidx + E;

  char* p = (char*)d_ws;
  auto alloc = [&](size_t bytes) {
    char* r = p;
    p += (bytes + 255) & ~(size_t)255;
    return r;
  };
  float* z = (float*)alloc((size_t)Nn * HIDC * 4);
  float* hbuf = (float*)alloc((size_t)Nn * HIDC * 4);
  float* R = (float*)alloc((size_t)Nn * HIDC * 4);  // T128 | s128, also O256
  ushort* WinTh = (ushort*)alloc(128 * 256 * 2);
  ushort* WinTl = (ushort*)alloc(128 * 256 * 2);
  ushort* W1Th = (ushort*)alloc((size_t)NLAYER * 256 * 128 * 2);
  ushort* W1Tl = (ushort*)alloc((size_t)NLAYER * 256 * 128 * 2);
  ushort* W2Th = (ushort*)alloc((size_t)NLAYER * 128 * 256 * 2);
  ushort* W2Tl = (ushort*)alloc((size_t)NLAYER * 128 * 256 * 2);
  ushort* U1Th = (ushort*)alloc((size_t)NLAYER * 256 * 256 * 2);
  ushort* U1Tl = (ushort*)alloc((size_t)NLAYER * 256 * 256 * 2);
  ushort* U2Th = (ushort*)alloc((size_t)NLAYER * 256 * 256 * 2);
  ushort* U2Tl = (ushort*)alloc((size_t)NLAYER * 256 * 256 * 2);
  int* deg = (int*)alloc((size_t)Nn * 4);
  int* rowptr = (int*)alloc((size_t)(Nn + 1) * 4);
  int* fillptr = (int*)alloc((size_t)Nn * 4);
  float* invc = (float*)alloc((size_t)Nn * 4);
  int* colv = (int*)alloc((size_t)E * 4);
  int* excl = (int*)alloc((size_t)Nn * 4);
  int* bsum = (int*)alloc(256 * 4);
  int* boff = (int*)alloc(256 * 4);
  float* betas = (float*)alloc(64);

  float* T128 = R;                      // [Nn x 128]
  float* s128 = R + (size_t)Nn * MSGC;  // [Nn x 128]
  float* Obuf = R;                      // [Nn x 256] (reuses T128+s128 region)

  const int nscan = (Nn + 255) / 256;

  // CSR build + betas + weight conversion
  hipMemsetAsync(deg, 0, (size_t)Nn * 4, stream);
  count_kernel<<<(E + 255) / 256, 256, 0, stream>>>(dstv, deg, E);
  scanA_kernel<<<nscan, 256, 0, stream>>>(deg, excl, bsum, Nn);
  scanB_kernel<<<1, 256, 0, stream>>>(bsum, boff, nscan);
  scanC_kernel<<<nscan, 256, 0, stream>>>(deg, excl, boff, rowptr, fillptr, invc, Nn, E);
  fill_kernel<<<(E + 255) / 256, 256, 0, stream>>>(srcv, dstv, fillptr, colv, E);
  beta_kernel<<<1, 64, 0, stream>>>(beta, betas);
  wconv_kernel<<<dim3(128, 1, 1), 256, 0, stream>>>(Win, WinTh, WinTl, 128, 256);
  wconv_kernel<<<dim3(128, 1, NLAYER), 256, 0, stream>>>(W1, W1Th, W1Tl, 256, 128);
  wconv_kernel<<<dim3(128, 1, NLAYER), 256, 0, stream>>>(W2, W2Th, W2Tl, 128, 256);
  wconv_kernel<<<dim3(256, 1, NLAYER), 256, 0, stream>>>(U1, U1Th, U1Tl, 256, 256);
  wconv_kernel<<<dim3(256, 1, NLAYER), 256, 0, stream>>>(U2, U2Th, U2Tl, 256, 256);

  const int mb128 = (Nn + 127) / 128;
  const int mb256 = (Nn + 255) / 256;
  const int nwave = (Nn + 3) / 4;

  // z0 = x @ Win + bin ; outp = betas[0]*z0
  gemm_big<0, 0, 2><<<mb256, 512, 0, stream>>>(x, WinTh, WinTl, bin_, nullptr, z,
                                               nullptr, nullptr, betas, 0, outp, Nn, 128);

  for (int l = 0; l < NLAYER; ++l) {
    // T128 = relu(z @ W1 + b1)   [N x 128]
    gemm_hilo<1><<<dim3(mb128, 1), 256, 0, stream>>>(
        z, W1Th + (size_t)l * 256 * 128, W1Tl + (size_t)l * 256 * 128, b1 + l * 128,
        T128, Nn, 256, 128);
    // s128 = segmean(T128)
    agg128_kernel<<<nwave, 256, 0, stream>>>(T128, rowptr, colv, invc, s128, Nn);
    // h = z + s128 @ W2 + b2     [N x 256]
    gemm_big<0, 1, 0><<<mb256, 512, 0, stream>>>(
        s128, W2Th + (size_t)l * 128 * 256, W2Tl + (size_t)l * 128 * 256, b2 + l * 256,
        z, hbuf, nullptr, nullptr, nullptr, 0, nullptr, Nn, 128);
    // O = relu(h @ U1 + c1)      [N x 256]
    gemm_big<1, 0, 0><<<mb256, 512, 0, stream>>>(
        hbuf, U1Th + (size_t)l * 256 * 256, U1Tl + (size_t)l * 256 * 256, c1 + l * 256,
        nullptr, Obuf, nullptr, nullptr, nullptr, 0, nullptr, Nn, 256);
    // z = LN(O @ U2 + c2)*g+b ; outp += betas[l+1]*z
    gemm_big<0, 0, 1><<<mb256, 512, 0, stream>>>(
        Obuf, U2Th + (size_t)l * 256 * 256, U2Tl + (size_t)l * 256 * 256, c2 + l * 256,
        nullptr, z, ln_g + l * 256, ln_b + l * 256, betas, l + 1, outp, Nn, 256);
  }
}

// Round 4
// 1990.154 us; speedup vs baseline: 1.5468x; 1.1815x over previous
//
#include <hip/hip_runtime.h>
#include <stdint.h>

typedef __attribute__((ext_vector_type(4))) float f32x4;
typedef __attribute__((ext_vector_type(2))) float f32x2;
typedef __attribute__((ext_vector_type(8))) short bf16x8;

#define HIDC 256
#define MSGC 128
#define NLAYER 10

__device__ __forceinline__ ushort f2bf(float f) {
  union { float f; uint32_t u; } a; a.f = f;
  uint32_t u = a.u;
  return (ushort)((u + 0x7fffu + ((u >> 16) & 1u)) >> 16);
}
__device__ __forceinline__ float bf2f(ushort h) {
  union { float f; uint32_t u; } a; a.u = ((uint32_t)h) << 16;
  return a.f;
}

// ---------------------------------------------------------------------------
// Small GEMM (W1, N=128): tile 128x128, 4 waves, BK=64. OUTBF16: C is ushort*.
// ---------------------------------------------------------------------------
template <int RELU, int OUTBF16>
__global__ __launch_bounds__(256, 2) void gemm_hilo(
    const float* __restrict__ A, const ushort* __restrict__ Bh,
    const ushort* __restrict__ Bl, const float* __restrict__ bias,
    float* __restrict__ C, int M, int K, int Nn) {
  __shared__ ushort lAh[128 * 64];
  __shared__ ushort lAl[128 * 64];
  __shared__ ushort lBh[128 * 64];
  __shared__ ushort lBl[128 * 64];
  const int tid = threadIdx.x;
  const int m0 = blockIdx.x * 128;
  const int n0 = blockIdx.y * 128;
  const int lane = tid & 63;
  const int w = tid >> 6;
  const int wm = (w >> 1) * 64;
  const int wn = (w & 1) * 64;
  const int rr = tid >> 3;
  const int cc = tid & 7;
  f32x4 acc[4][4] = {};

  const int nsteps = K >> 6;
  for (int s = 0; s < nsteps; ++s) {
    const int k0 = s * 64;
#pragma unroll
    for (int p = 0; p < 4; ++p) {
      const int row = p * 32 + rr;
      const int gm = m0 + row;
      f32x4 va = {0.f, 0.f, 0.f, 0.f}, vb = {0.f, 0.f, 0.f, 0.f};
      if (gm < M) {
        const float* ga = A + (size_t)gm * K + k0 + cc * 8;
        va = *(const f32x4*)ga;
        vb = *(const f32x4*)(ga + 4);
      }
      bf16x8 hv, lv;
#pragma unroll
      for (int e = 0; e < 4; ++e) {
        float v = va[e];
        ushort hh = f2bf(v);
        hv[e] = (short)hh;
        lv[e] = (short)f2bf(v - bf2f(hh));
        float v2 = vb[e];
        ushort hh2 = f2bf(v2);
        hv[e + 4] = (short)hh2;
        lv[e + 4] = (short)f2bf(v2 - bf2f(hh2));
      }
      const uint32_t off = (uint32_t)((row * 128 + cc * 16) ^ ((row & 7) << 4));
      *(bf16x8*)((char*)lAh + off) = hv;
      *(bf16x8*)((char*)lAl + off) = lv;
    }
#pragma unroll
    for (int p = 0; p < 4; ++p) {
      const int row = p * 32 + rr;
      const size_t gb = (size_t)(n0 + row) * K + k0 + cc * 8;
      bf16x8 bh = *(const bf16x8*)(Bh + gb);
      bf16x8 bl = *(const bf16x8*)(Bl + gb);
      const uint32_t off = (uint32_t)((row * 128 + cc * 16) ^ ((row & 7) << 4));
      *(bf16x8*)((char*)lBh + off) = bh;
      *(bf16x8*)((char*)lBl + off) = bl;
    }
    __syncthreads();
#pragma unroll
    for (int kk = 0; kk < 2; ++kk) {
      bf16x8 ah[4], al[4], bh[4], bl[4];
#pragma unroll
      for (int i = 0; i < 4; ++i) {
        const int arow = wm + i * 16 + (lane & 15);
        const uint32_t ao =
            (uint32_t)((arow * 128 + kk * 64 + ((lane >> 4) * 16)) ^ ((arow & 7) << 4));
        ah[i] = *(const bf16x8*)((const char*)lAh + ao);
        al[i] = *(const bf16x8*)((const char*)lAl + ao);
        const int brow = wn + i * 16 + (lane & 15);
        const uint32_t bo =
            (uint32_t)((brow * 128 + kk * 64 + ((lane >> 4) * 16)) ^ ((brow & 7) << 4));
        bh[i] = *(const bf16x8*)((const char*)lBh + bo);
        bl[i] = *(const bf16x8*)((const char*)lBl + bo);
      }
#pragma unroll
      for (int i = 0; i < 4; ++i)
#pragma unroll
        for (int j = 0; j < 4; ++j) {
          acc[i][j] = __builtin_amdgcn_mfma_f32_16x16x32_bf16(ah[i], bh[j], acc[i][j], 0, 0, 0);
          acc[i][j] = __builtin_amdgcn_mfma_f32_16x16x32_bf16(ah[i], bl[j], acc[i][j], 0, 0, 0);
          acc[i][j] = __builtin_amdgcn_mfma_f32_16x16x32_bf16(al[i], bh[j], acc[i][j], 0, 0, 0);
        }
    }
    __syncthreads();
  }
  float bi[4];
#pragma unroll
  for (int j = 0; j < 4; ++j) bi[j] = bias[n0 + wn + j * 16 + (lane & 15)];
#pragma unroll
  for (int i = 0; i < 4; ++i) {
    const int gm0 = m0 + wm + i * 16 + ((lane >> 4) << 2);
#pragma unroll
    for (int r = 0; r < 4; ++r) {
      const int gm = gm0 + r;
      if (gm < M) {
        const size_t base = (size_t)gm * Nn + n0 + wn + (lane & 15);
#pragma unroll
        for (int j = 0; j < 4; ++j) {
          float v = acc[i][j][r] + bi[j];
          if (RELU) v = fmaxf(v, 0.f);
          if (OUTBF16) {
            ((ushort*)C)[base + j * 16] = f2bf(v);
          } else {
            C[base + j * 16] = v;
          }
        }
      }
    }
  }
}

// ---------------------------------------------------------------------------
// Big GEMM: tile 256x256, 8 waves (512 thr), BK=64, N fixed = 256.
// MODE 0: C = act(A@B^T + bias [+Z])
// MODE 1: y = LN(A@B^T + bias)*g + b_; C = y; outp += betas[lidx]*y
// MODE 2: C = A@B^T + bias; outp = betas[lidx]*C   (z0 path)
// ---------------------------------------------------------------------------
template <int RELU, int ADDZ, int MODE>
__global__ __launch_bounds__(512, 2) void gemm_big(
    const float* __restrict__ A, const ushort* __restrict__ Bh,
    const ushort* __restrict__ Bl, const float* __restrict__ bias,
    const float* __restrict__ Z, float* __restrict__ C,
    const float* __restrict__ g, const float* __restrict__ b_,
    const float* __restrict__ betas, int lidx, float* __restrict__ outp,
    int M, int K) {
  __shared__ ushort lAh[256 * 64];
  __shared__ ushort lAl[256 * 64];
  __shared__ ushort lBh[256 * 64];
  __shared__ ushort lBl[256 * 64];
  __shared__ float sstat[2][2][256];
  const int tid = threadIdx.x;
  const int m0 = blockIdx.x * 256;
  const int lane = tid & 63;
  const int w = tid >> 6;
  const int wm = (w >> 1) * 64;
  const int wn = (w & 1) * 128;
  const int rr = tid >> 3;
  const int cc = tid & 7;
  f32x4 acc[4][8] = {};

  const int nsteps = K >> 6;
  for (int s = 0; s < nsteps; ++s) {
    const int k0 = s * 64;
#pragma unroll
    for (int p = 0; p < 4; ++p) {
      const int row = p * 64 + rr;
      const int gm = m0 + row;
      f32x4 va = {0.f, 0.f, 0.f, 0.f}, vb = {0.f, 0.f, 0.f, 0.f};
      if (gm < M) {
        const float* ga = A + (size_t)gm * K + k0 + cc * 8;
        va = *(const f32x4*)ga;
        vb = *(const f32x4*)(ga + 4);
      }
      bf16x8 hv, lv;
#pragma unroll
      for (int e = 0; e < 4; ++e) {
        float v = va[e];
        ushort hh = f2bf(v);
        hv[e] = (short)hh;
        lv[e] = (short)f2bf(v - bf2f(hh));
        float v2 = vb[e];
        ushort hh2 = f2bf(v2);
        hv[e + 4] = (short)hh2;
        lv[e + 4] = (short)f2bf(v2 - bf2f(hh2));
      }
      const uint32_t off = (uint32_t)((row * 128 + cc * 16) ^ ((row & 7) << 4));
      *(bf16x8*)((char*)lAh + off) = hv;
      *(bf16x8*)((char*)lAl + off) = lv;
    }
#pragma unroll
    for (int p = 0; p < 4; ++p) {
      const int row = p * 64 + rr;
      const size_t gb = (size_t)row * K + k0 + cc * 8;
      bf16x8 bh = *(const bf16x8*)(Bh + gb);
      bf16x8 bl = *(const bf16x8*)(Bl + gb);
      const uint32_t off = (uint32_t)((row * 128 + cc * 16) ^ ((row & 7) << 4));
      *(bf16x8*)((char*)lBh + off) = bh;
      *(bf16x8*)((char*)lBl + off) = bl;
    }
    __syncthreads();
#pragma unroll
    for (int kk = 0; kk < 2; ++kk) {
      bf16x8 ah[4], al[4];
#pragma unroll
      for (int i = 0; i < 4; ++i) {
        const int arow = wm + i * 16 + (lane & 15);
        const uint32_t ao =
            (uint32_t)((arow * 128 + kk * 64 + ((lane >> 4) * 16)) ^ ((arow & 7) << 4));
        ah[i] = *(const bf16x8*)((const char*)lAh + ao);
        al[i] = *(const bf16x8*)((const char*)lAl + ao);
      }
#pragma unroll
      for (int jc = 0; jc < 2; ++jc) {
        bf16x8 bh[4], bl[4];
#pragma unroll
        for (int jj = 0; jj < 4; ++jj) {
          const int brow = wn + jc * 64 + jj * 16 + (lane & 15);
          const uint32_t bo =
              (uint32_t)((brow * 128 + kk * 64 + ((lane >> 4) * 16)) ^ ((brow & 7) << 4));
          bh[jj] = *(const bf16x8*)((const char*)lBh + bo);
          bl[jj] = *(const bf16x8*)((const char*)lBl + bo);
        }
#pragma unroll
        for (int i = 0; i < 4; ++i)
#pragma unroll
          for (int jj = 0; jj < 4; ++jj) {
            const int j = jc * 4 + jj;
            acc[i][j] = __builtin_amdgcn_mfma_f32_16x16x32_bf16(ah[i], bh[jj], acc[i][j], 0, 0, 0);
            acc[i][j] = __builtin_amdgcn_mfma_f32_16x16x32_bf16(ah[i], bl[jj], acc[i][j], 0, 0, 0);
            acc[i][j] = __builtin_amdgcn_mfma_f32_16x16x32_bf16(al[i], bh[jj], acc[i][j], 0, 0, 0);
          }
      }
    }
    __syncthreads();
  }

  float bi[8];
#pragma unroll
  for (int j = 0; j < 8; ++j) bi[j] = bias[wn + j * 16 + (lane & 15)];

  if (MODE == 1) {
    float gv[8], bv[8];
#pragma unroll
    for (int j = 0; j < 8; ++j) {
      gv[j] = g[wn + j * 16 + (lane & 15)];
      bv[j] = b_[wn + j * 16 + (lane & 15)];
    }
    const float beta_s = betas[lidx];
#pragma unroll
    for (int i = 0; i < 4; ++i) {
#pragma unroll
      for (int r = 0; r < 4; ++r) {
        float s1 = 0.f, s2 = 0.f;
#pragma unroll
        for (int j = 0; j < 8; ++j) {
          float v = acc[i][j][r] + bi[j];
          acc[i][j][r] = v;
          s1 += v;
          s2 += v * v;
        }
#pragma unroll
        for (int d = 1; d < 16; d <<= 1) {
          s1 += __shfl_xor(s1, d);
          s2 += __shfl_xor(s2, d);
        }
        if ((lane & 15) == 0) {
          const int rl = wm + i * 16 + ((lane >> 4) << 2) + r;
          sstat[0][w & 1][rl] = s1;
          sstat[1][w & 1][rl] = s2;
        }
      }
    }
    __syncthreads();
#pragma unroll
    for (int i = 0; i < 4; ++i) {
#pragma unroll
      for (int r = 0; r < 4; ++r) {
        const int rl = wm + i * 16 + ((lane >> 4) << 2) + r;
        const float s1 = sstat[0][0][rl] + sstat[0][1][rl];
        const float s2 = sstat[1][0][rl] + sstat[1][1][rl];
        const float mu = s1 * (1.f / 256.f);
        const float var = s2 * (1.f / 256.f) - mu * mu;
        const float rs = rsqrtf(var + 1e-5f);
        const int gm = m0 + rl;
        if (gm < M) {
          const size_t base = (size_t)gm * 256 + wn + (lane & 15);
#pragma unroll
          for (int j = 0; j < 8; ++j) {
            const float y = (acc[i][j][r] - mu) * rs * gv[j] + bv[j];
            const size_t o = base + j * 16;
            C[o] = y;
            outp[o] = outp[o] + beta_s * y;
          }
        }
      }
    }
  } else {
    const float beta_s = (MODE == 2) ? betas[lidx] : 0.f;
#pragma unroll
    for (int i = 0; i < 4; ++i) {
      const int gm0 = m0 + wm + i * 16 + ((lane >> 4) << 2);
#pragma unroll
      for (int r = 0; r < 4; ++r) {
        const int gm = gm0 + r;
        if (gm < M) {
          const size_t base = (size_t)gm * 256 + wn + (lane & 15);
#pragma unroll
          for (int j = 0; j < 8; ++j) {
            float v = acc[i][j][r] + bi[j];
            if (ADDZ) v += Z[base + j * 16];
            if (RELU) v = fmaxf(v, 0.f);
            C[base + j * 16] = v;
            if (MODE == 2) outp[base + j * 16] = beta_s * v;
          }
        }
      }
    }
  }
}

// ---------------------------------------------------------------------------
// CSR build (parallel scan)
// ---------------------------------------------------------------------------
__global__ void count_kernel(const int* __restrict__ dstv, int* __restrict__ deg, int E) {
  int i = blockIdx.x * 256 + threadIdx.x;
  if (i < E) atomicAdd(&deg[dstv[i]], 1);
}

__global__ void scanA_kernel(const int* __restrict__ deg, int* __restrict__ excl,
                             int* __restrict__ bsum, int n) {
  __shared__ int sm[256];
  const int i = blockIdx.x * 256 + threadIdx.x;
  const int v = (i < n) ? deg[i] : 0;
  sm[threadIdx.x] = v;
  __syncthreads();
  for (int off = 1; off < 256; off <<= 1) {
    int t = (threadIdx.x >= off) ? sm[threadIdx.x - off] : 0;
    __syncthreads();
    sm[threadIdx.x] += t;
    __syncthreads();
  }
  if (i < n) excl[i] = sm[threadIdx.x] - v;
  if (threadIdx.x == 255) bsum[blockIdx.x] = sm[255];
}

__global__ void scanB_kernel(const int* __restrict__ bsum, int* __restrict__ boff, int nb) {
  __shared__ int sm[256];
  const int v = (threadIdx.x < nb) ? bsum[threadIdx.x] : 0;
  sm[threadIdx.x] = v;
  __syncthreads();
  for (int off = 1; off < 256; off <<= 1) {
    int t = (threadIdx.x >= off) ? sm[threadIdx.x - off] : 0;
    __syncthreads();
    sm[threadIdx.x] += t;
    __syncthreads();
  }
  if (threadIdx.x < nb) boff[threadIdx.x] = sm[threadIdx.x] - v;
}

__global__ void scanC_kernel(const int* __restrict__ deg, const int* __restrict__ excl,
                             const int* __restrict__ boff, int* __restrict__ rowptr,
                             int* __restrict__ fillptr, float* __restrict__ invc,
                             int n, int E) {
  const int i = blockIdx.x * 256 + threadIdx.x;
  if (i < n) {
    const int r = excl[i] + boff[blockIdx.x];
    rowptr[i] = r;
    fillptr[i] = r;
    invc[i] = 1.0f / (float)(deg[i] + 1);
  }
  if (i == 0) rowptr[n] = E;
}

__global__ void fill_kernel(const int* __restrict__ srcv, const int* __restrict__ dstv,
                            int* __restrict__ fillptr, int* __restrict__ colv, int E) {
  int i = blockIdx.x * 256 + threadIdx.x;
  if (i < E) {
    int p = atomicAdd(&fillptr[dstv[i]], 1);
    colv[p] = srcv[i];
  }
}

// ---------------------------------------------------------------------------
// 128-d aggregation over bf16 T: s[v] = (T[v] + sum_edges T[src]) * invc[v]
// one wave per node; lane covers 2 cols via one u32 (2xbf16) load.
// ---------------------------------------------------------------------------
__global__ __launch_bounds__(256) void agg128_kernel(
    const uint32_t* __restrict__ T, const int* __restrict__ rowptr,
    const int* __restrict__ colv, const float* __restrict__ invc,
    float* __restrict__ sout, int n) {
  const int node = blockIdx.x * 4 + (threadIdx.x >> 6);
  if (node >= n) return;
  const int lane = threadIdx.x & 63;
  auto up0 = [](uint32_t u) {
    union { uint32_t u; float f; } a; a.u = u << 16; return a.f;
  };
  auto up1 = [](uint32_t u) {
    union { uint32_t u; float f; } a; a.u = u & 0xffff0000u; return a.f;
  };
  uint32_t self = T[(size_t)node * 64 + lane];
  float a0 = up0(self), a1 = up1(self);
  float b0 = 0.f, b1 = 0.f;
  const int s = rowptr[node];
  const int e = rowptr[node + 1];
  int i = s;
  for (; i + 1 < e; i += 2) {
    const int s0 = colv[i];
    const int s1i = colv[i + 1];
    const uint32_t u0 = T[(size_t)s0 * 64 + lane];
    const uint32_t u1 = T[(size_t)s1i * 64 + lane];
    a0 += up0(u0); a1 += up1(u0);
    b0 += up0(u1); b1 += up1(u1);
  }
  if (i < e) {
    const uint32_t u0 = T[(size_t)colv[i] * 64 + lane];
    a0 += up0(u0); a1 += up1(u0);
  }
  const float ic = invc[node];
  f32x2 r;
  r[0] = (a0 + b0) * ic;
  r[1] = (a1 + b1) * ic;
  ((f32x2*)sout)[(size_t)node * 64 + lane] = r;
}

__global__ void beta_kernel(const float* __restrict__ beta, float* __restrict__ betas) {
  if (threadIdx.x == 0) {
    float mx = beta[0];
    for (int i = 1; i < NLAYER + 1; ++i) mx = fmaxf(mx, beta[i]);
    float e[NLAYER + 1];
    float s = 0.f;
    for (int i = 0; i < NLAYER + 1; ++i) {
      e[i] = expf(beta[i] - mx);
      s += e[i];
    }
    const float inv = 1.f / s;
    for (int i = 0; i < NLAYER + 1; ++i) betas[i] = e[i] * inv;
  }
}

// W[K][N] f32 -> Wt_hi[N][K], Wt_lo[N][K] bf16 (output-index coalesced)
__global__ void wconv_kernel(const float* __restrict__ W, ushort* __restrict__ Wh,
                             ushort* __restrict__ Wl, int K, int Nn) {
  const size_t matoff = (size_t)blockIdx.z * K * Nn;
  const int o = blockIdx.x * 256 + threadIdx.x;
  if (o >= K * Nn) return;
  const int nn = o / K;
  const int kk = o - nn * K;
  const float v = W[matoff + (size_t)kk * Nn + nn];
  const ushort hh = f2bf(v);
  Wh[matoff + o] = hh;
  Wl[matoff + o] = f2bf(v - bf2f(hh));
}

// ---------------------------------------------------------------------------
extern "C" void kernel_launch(void* const* d_in, const int* in_sizes, int n_in,
                              void* d_out, int out_size, void* d_ws, size_t ws_size,
                              hipStream_t stream) {
  const float* x = (const float*)d_in[0];
  const int* eidx = (const int*)d_in[1];
  const float* Win = (const float*)d_in[2];
  const float* bin_ = (const float*)d_in[3];
  const float* W1 = (const float*)d_in[4];
  const float* b1 = (const float*)d_in[5];
  const float* W2 = (const float*)d_in[6];
  const float* b2 = (const float*)d_in[7];
  const float* U1 = (const float*)d_in[8];
  const float* c1 = (const float*)d_in[9];
  const float* U2 = (const float*)d_in[10];
  const float* c2 = (const float*)d_in[11];
  const float* ln_g = (const float*)d_in[12];
  const float* ln_b = (const float*)d_in[13];
  const float* beta = (const float*)d_in[14];
  float* outp = (float*)d_out;

  const int Nn = in_sizes[0] / 128;  // 50000
  const int E = in_sizes[1] / 2;     // 800000
  const int* srcv = eidx;
  const int* dstv = eidx + E;

  char* p = (char*)d_ws;
  auto alloc = [&](size_t bytes) {
    char* r = p;
    p += (bytes + 255) & ~(size_t)255;
    return r;
  };
  float* z = (float*)alloc((size_t)Nn * HIDC * 4);
  float* hbuf = (float*)alloc((size_t)Nn * HIDC * 4);
  float* R = (float*)alloc((size_t)Nn * HIDC * 4);  // T128(bf16) | s128, also O256
  ushort* WinTh = (ushort*)alloc(128 * 256 * 2);
  ushort* WinTl = (ushort*)alloc(128 * 256 * 2);
  ushort* W1Th = (ushort*)alloc((size_t)NLAYER * 256 * 128 * 2);
  ushort* W1Tl = (ushort*)alloc((size_t)NLAYER * 256 * 128 * 2);
  ushort* W2Th = (ushort*)alloc((size_t)NLAYER * 128 * 256 * 2);
  ushort* W2Tl = (ushort*)alloc((size_t)NLAYER * 128 * 256 * 2);
  ushort* U1Th = (ushort*)alloc((size_t)NLAYER * 256 * 256 * 2);
  ushort* U1Tl = (ushort*)alloc((size_t)NLAYER * 256 * 256 * 2);
  ushort* U2Th = (ushort*)alloc((size_t)NLAYER * 256 * 256 * 2);
  ushort* U2Tl = (ushort*)alloc((size_t)NLAYER * 256 * 256 * 2);
  int* deg = (int*)alloc((size_t)Nn * 4);
  int* rowptr = (int*)alloc((size_t)(Nn + 1) * 4);
  int* fillptr = (int*)alloc((size_t)Nn * 4);
  float* invc = (float*)alloc((size_t)Nn * 4);
  int* colv = (int*)alloc((size_t)E * 4);
  int* excl = (int*)alloc((size_t)Nn * 4);
  int* bsum = (int*)alloc(256 * 4);
  int* boff = (int*)alloc(256 * 4);
  float* betas = (float*)alloc(64);

  ushort* T128 = (ushort*)R;                          // [Nn x 128] bf16
  float* s128 = (float*)((char*)R + (size_t)Nn * MSGC * 2);  // [Nn x 128] f32
  float* Obuf = R;                                    // [Nn x 256] f32 (reuse)

  const int nscan = (Nn + 255) / 256;

  hipMemsetAsync(deg, 0, (size_t)Nn * 4, stream);
  count_kernel<<<(E + 255) / 256, 256, 0, stream>>>(dstv, deg, E);
  scanA_kernel<<<nscan, 256, 0, stream>>>(deg, excl, bsum, Nn);
  scanB_kernel<<<1, 256, 0, stream>>>(bsum, boff, nscan);
  scanC_kernel<<<nscan, 256, 0, stream>>>(deg, excl, boff, rowptr, fillptr, invc, Nn, E);
  fill_kernel<<<(E + 255) / 256, 256, 0, stream>>>(srcv, dstv, fillptr, colv, E);
  beta_kernel<<<1, 64, 0, stream>>>(beta, betas);
  wconv_kernel<<<dim3(128, 1, 1), 256, 0, stream>>>(Win, WinTh, WinTl, 128, 256);
  wconv_kernel<<<dim3(128, 1, NLAYER), 256, 0, stream>>>(W1, W1Th, W1Tl, 256, 128);
  wconv_kernel<<<dim3(128, 1, NLAYER), 256, 0, stream>>>(W2, W2Th, W2Tl, 128, 256);
  wconv_kernel<<<dim3(256, 1, NLAYER), 256, 0, stream>>>(U1, U1Th, U1Tl, 256, 256);
  wconv_kernel<<<dim3(256, 1, NLAYER), 256, 0, stream>>>(U2, U2Th, U2Tl, 256, 256);

  const int mb128 = (Nn + 127) / 128;
  const int mb256 = (Nn + 255) / 256;
  const int nwave = (Nn + 3) / 4;

  // z0 = x @ Win + bin ; outp = betas[0]*z0
  gemm_big<0, 0, 2><<<mb256, 512, 0, stream>>>(x, WinTh, WinTl, bin_, nullptr, z,
                                               nullptr, nullptr, betas, 0, outp, Nn, 128);

  for (int l = 0; l < NLAYER; ++l) {
    // T128(bf16) = relu(z @ W1 + b1)   [N x 128]
    gemm_hilo<1, 1><<<dim3(mb128, 1), 256, 0, stream>>>(
        z, W1Th + (size_t)l * 256 * 128, W1Tl + (size_t)l * 256 * 128, b1 + l * 128,
        (float*)T128, Nn, 256, 128);
    // s128 = segmean(T128)
    agg128_kernel<<<nwave, 256, 0, stream>>>((const uint32_t*)T128, rowptr, colv, invc,
                                             s128, Nn);
    // h = z + s128 @ W2 + b2     [N x 256]
    gemm_big<0, 1, 0><<<mb256, 512, 0, stream>>>(
        s128, W2Th + (size_t)l * 128 * 256, W2Tl + (size_t)l * 128 * 256, b2 + l * 256,
        z, hbuf, nullptr, nullptr, nullptr, 0, nullptr, Nn, 128);
    // O = relu(h @ U1 + c1)      [N x 256]
    gemm_big<1, 0, 0><<<mb256, 512, 0, stream>>>(
        hbuf, U1Th + (size_t)l * 256 * 256, U1Tl + (size_t)l * 256 * 256, c1 + l * 256,
        nullptr, Obuf, nullptr, nullptr, nullptr, 0, nullptr, Nn, 256);
    // z = LN(O @ U2 + c2)*g+b ; outp += betas[l+1]*z
    gemm_big<0, 0, 1><<<mb256, 512, 0, stream>>>(
        Obuf, U2Th + (size_t)l * 256 * 256, U2Tl + (size_t)l * 256 * 256, c2 + l * 256,
        nullptr, z, ln_g + l * 256, ln_b + l * 256, betas, l + 1, outp, Nn, 256);
  }
}

// Round 6
// 1878.221 us; speedup vs baseline: 1.6390x; 1.0596x over previous
//
#include <hip/hip_runtime.h>
#include <stdint.h>

typedef __attribute__((ext_vector_type(4))) float f32x4;
typedef __attribute__((ext_vector_type(2))) float f32x2;
typedef __attribute__((ext_vector_type(8))) short bf16x8;

#define HIDC 256
#define MSGC 128
#define NLAYER 10

__device__ __forceinline__ ushort f2bf(float f) {
  union { float f; uint32_t u; } a; a.f = f;
  uint32_t u = a.u;
  return (ushort)((u + 0x7fffu + ((u >> 16) & 1u)) >> 16);
}
__device__ __forceinline__ float bf2f(ushort h) {
  union { float f; uint32_t u; } a; a.u = ((uint32_t)h) << 16;
  return a.f;
}

// ---------------------------------------------------------------------------
// Small GEMM (W1, N=128): tile 128x128, 4 waves, BK=64. OUTBF16: C is ushort*.
// ---------------------------------------------------------------------------
template <int RELU, int OUTBF16>
__global__ __launch_bounds__(256, 2) void gemm_hilo(
    const float* __restrict__ A, const ushort* __restrict__ Bh,
    const ushort* __restrict__ Bl, const float* __restrict__ bias,
    float* __restrict__ C, int M, int K, int Nn) {
  __shared__ ushort lAh[128 * 64];
  __shared__ ushort lAl[128 * 64];
  __shared__ ushort lBh[128 * 64];
  __shared__ ushort lBl[128 * 64];
  const int tid = threadIdx.x;
  const int m0 = blockIdx.x * 128;
  const int n0 = blockIdx.y * 128;
  const int lane = tid & 63;
  const int w = tid >> 6;
  const int wm = (w >> 1) * 64;
  const int wn = (w & 1) * 64;
  const int rr = tid >> 3;
  const int cc = tid & 7;
  f32x4 acc[4][4] = {};

  const int nsteps = K >> 6;
  for (int s = 0; s < nsteps; ++s) {
    const int k0 = s * 64;
#pragma unroll
    for (int p = 0; p < 4; ++p) {
      const int row = p * 32 + rr;
      const int gm = m0 + row;
      f32x4 va = {0.f, 0.f, 0.f, 0.f}, vb = {0.f, 0.f, 0.f, 0.f};
      if (gm < M) {
        const float* ga = A + (size_t)gm * K + k0 + cc * 8;
        va = *(const f32x4*)ga;
        vb = *(const f32x4*)(ga + 4);
      }
      bf16x8 hv, lv;
#pragma unroll
      for (int e = 0; e < 4; ++e) {
        float v = va[e];
        ushort hh = f2bf(v);
        hv[e] = (short)hh;
        lv[e] = (short)f2bf(v - bf2f(hh));
        float v2 = vb[e];
        ushort hh2 = f2bf(v2);
        hv[e + 4] = (short)hh2;
        lv[e + 4] = (short)f2bf(v2 - bf2f(hh2));
      }
      const uint32_t off = (uint32_t)((row * 128 + cc * 16) ^ ((row & 7) << 4));
      *(bf16x8*)((char*)lAh + off) = hv;
      *(bf16x8*)((char*)lAl + off) = lv;
    }
#pragma unroll
    for (int p = 0; p < 4; ++p) {
      const int row = p * 32 + rr;
      const size_t gb = (size_t)(n0 + row) * K + k0 + cc * 8;
      bf16x8 bh = *(const bf16x8*)(Bh + gb);
      bf16x8 bl = *(const bf16x8*)(Bl + gb);
      const uint32_t off = (uint32_t)((row * 128 + cc * 16) ^ ((row & 7) << 4));
      *(bf16x8*)((char*)lBh + off) = bh;
      *(bf16x8*)((char*)lBl + off) = bl;
    }
    __syncthreads();
#pragma unroll
    for (int kk = 0; kk < 2; ++kk) {
      bf16x8 ah[4], al[4], bh[4], bl[4];
#pragma unroll
      for (int i = 0; i < 4; ++i) {
        const int arow = wm + i * 16 + (lane & 15);
        const uint32_t ao =
            (uint32_t)((arow * 128 + kk * 64 + ((lane >> 4) * 16)) ^ ((arow & 7) << 4));
        ah[i] = *(const bf16x8*)((const char*)lAh + ao);
        al[i] = *(const bf16x8*)((const char*)lAl + ao);
        const int brow = wn + i * 16 + (lane & 15);
        const uint32_t bo =
            (uint32_t)((brow * 128 + kk * 64 + ((lane >> 4) * 16)) ^ ((brow & 7) << 4));
        bh[i] = *(const bf16x8*)((const char*)lBh + bo);
        bl[i] = *(const bf16x8*)((const char*)lBl + bo);
      }
#pragma unroll
      for (int i = 0; i < 4; ++i)
#pragma unroll
        for (int j = 0; j < 4; ++j) {
          acc[i][j] = __builtin_amdgcn_mfma_f32_16x16x32_bf16(ah[i], bh[j], acc[i][j], 0, 0, 0);
          acc[i][j] = __builtin_amdgcn_mfma_f32_16x16x32_bf16(ah[i], bl[j], acc[i][j], 0, 0, 0);
          acc[i][j] = __builtin_amdgcn_mfma_f32_16x16x32_bf16(al[i], bh[j], acc[i][j], 0, 0, 0);
        }
    }
    __syncthreads();
  }
  float bi[4];
#pragma unroll
  for (int j = 0; j < 4; ++j) bi[j] = bias[n0 + wn + j * 16 + (lane & 15)];
#pragma unroll
  for (int i = 0; i < 4; ++i) {
    const int gm0 = m0 + wm + i * 16 + ((lane >> 4) << 2);
#pragma unroll
    for (int r = 0; r < 4; ++r) {
      const int gm = gm0 + r;
      if (gm < M) {
        const size_t base = (size_t)gm * Nn + n0 + wn + (lane & 15);
#pragma unroll
        for (int j = 0; j < 4; ++j) {
          float v = acc[i][j][r] + bi[j];
          if (RELU) v = fmaxf(v, 0.f);
          if (OUTBF16) {
            ((ushort*)C)[base + j * 16] = f2bf(v);
          } else {
            C[base + j * 16] = v;
          }
        }
      }
    }
  }
}

// ---------------------------------------------------------------------------
// Big GEMM: tile 128x256, 8 waves (512 thr), BK=32, N fixed = 256.
// 52 KB LDS -> 2 blocks/CU; grid = ceil(M/128) = 391 fills all CUs.
// MODE 0: C = act(A@B^T + bias [+Z])
// MODE 1: y = LN(A@B^T+bias)*g+b_; C = y; ZH = bf16(y)
// MODE 2: C = A@B^T + bias; ZH = bf16(C)            (z0, zhist path)
// MODE 3: y = LN(A@B^T+bias)*g+b_; C = y; outp += betas[lidx]*y
// MODE 4: C = A@B^T + bias; outp = betas[lidx]*C    (z0, fallback path)
// ---------------------------------------------------------------------------
template <int RELU, int ADDZ, int MODE>
__global__ __launch_bounds__(512, 4) void gemm_big(
    const float* __restrict__ A, const ushort* __restrict__ Bh,
    const ushort* __restrict__ Bl, const float* __restrict__ bias,
    const float* __restrict__ Z, float* __restrict__ C,
    const float* __restrict__ g, const float* __restrict__ b_,
    ushort* __restrict__ ZH, const float* __restrict__ betas, int lidx,
    float* __restrict__ outp, int M, int K) {
  __shared__ ushort lAh[128 * 32];
  __shared__ ushort lAl[128 * 32];
  __shared__ ushort lBh[256 * 32];
  __shared__ ushort lBl[256 * 32];
  __shared__ float sstat[2][4][128];
  const int tid = threadIdx.x;
  const int m0 = blockIdx.x * 128;
  const int lane = tid & 63;
  const int w = tid >> 6;        // 0..7
  const int wm = (w >> 2) * 64;  // 0,64
  const int wn = (w & 3) * 64;   // 0,64,128,192
  const int srow = tid >> 2;     // 0..127
  const int cc = tid & 3;        // 0..3
  f32x4 acc[4][4] = {};

  const int nsteps = K >> 5;
  for (int s = 0; s < nsteps; ++s) {
    const int k0 = s * 32;
    // ---- stage A: 128 rows x 32 f32 -> hi/lo bf16, one pass
    {
      const int gm = m0 + srow;
      f32x4 va = {0.f, 0.f, 0.f, 0.f}, vb = {0.f, 0.f, 0.f, 0.f};
      if (gm < M) {
        const float* ga = A + (size_t)gm * K + k0 + cc * 8;
        va = *(const f32x4*)ga;
        vb = *(const f32x4*)(ga + 4);
      }
      bf16x8 hv, lv;
#pragma unroll
      for (int e = 0; e < 4; ++e) {
        float v = va[e];
        ushort hh = f2bf(v);
        hv[e] = (short)hh;
        lv[e] = (short)f2bf(v - bf2f(hh));
        float v2 = vb[e];
        ushort hh2 = f2bf(v2);
        hv[e + 4] = (short)hh2;
        lv[e + 4] = (short)f2bf(v2 - bf2f(hh2));
      }
      const uint32_t off = (uint32_t)((srow * 64 + cc * 16) ^ ((srow & 3) << 4));
      *(bf16x8*)((char*)lAh + off) = hv;
      *(bf16x8*)((char*)lAl + off) = lv;
    }
    // ---- stage B: 256 rows x 32 bf16 hi/lo, 2 passes of 128 rows
#pragma unroll
    for (int p = 0; p < 2; ++p) {
      const int brow = p * 128 + srow;
      const size_t gb = (size_t)brow * K + k0 + cc * 8;
      bf16x8 bh = *(const bf16x8*)(Bh + gb);
      bf16x8 bl = *(const bf16x8*)(Bl + gb);
      const uint32_t off = (uint32_t)((brow * 64 + cc * 16) ^ ((brow & 3) << 4));
      *(bf16x8*)((char*)lBh + off) = bh;
      *(bf16x8*)((char*)lBl + off) = bl;
    }
    __syncthreads();
    // ---- compute: one k-substep of 32
    {
      bf16x8 ah[4], al[4];
#pragma unroll
      for (int i = 0; i < 4; ++i) {
        const int arow = wm + i * 16 + (lane & 15);
        const uint32_t ao =
            (uint32_t)((arow * 64 + ((lane >> 4) * 16)) ^ ((arow & 3) << 4));
        ah[i] = *(const bf16x8*)((const char*)lAh + ao);
        al[i] = *(const bf16x8*)((const char*)lAl + ao);
      }
#pragma unroll
      for (int j = 0; j < 4; ++j) {
        const int brow = wn + j * 16 + (lane & 15);
        const uint32_t bo =
            (uint32_t)((brow * 64 + ((lane >> 4) * 16)) ^ ((brow & 3) << 4));
        const bf16x8 bh = *(const bf16x8*)((const char*)lBh + bo);
        const bf16x8 bl = *(const bf16x8*)((const char*)lBl + bo);
#pragma unroll
        for (int i = 0; i < 4; ++i) {
          acc[i][j] = __builtin_amdgcn_mfma_f32_16x16x32_bf16(ah[i], bh, acc[i][j], 0, 0, 0);
          acc[i][j] = __builtin_amdgcn_mfma_f32_16x16x32_bf16(ah[i], bl, acc[i][j], 0, 0, 0);
          acc[i][j] = __builtin_amdgcn_mfma_f32_16x16x32_bf16(al[i], bh, acc[i][j], 0, 0, 0);
        }
      }
    }
    __syncthreads();
  }

  // ---- epilogue: frag row = wm + i*16 + (lane>>4)*4 + r, col = wn + j*16 + (lane&15)
  float bi[4];
#pragma unroll
  for (int j = 0; j < 4; ++j) bi[j] = bias[wn + j * 16 + (lane & 15)];

  if (MODE == 1 || MODE == 3) {
    float gv[4], bv[4];
#pragma unroll
    for (int j = 0; j < 4; ++j) {
      gv[j] = g[wn + j * 16 + (lane & 15)];
      bv[j] = b_[wn + j * 16 + (lane & 15)];
    }
#pragma unroll
    for (int i = 0; i < 4; ++i) {
#pragma unroll
      for (int r = 0; r < 4; ++r) {
        float s1 = 0.f, s2 = 0.f;
#pragma unroll
        for (int j = 0; j < 4; ++j) {
          float v = acc[i][j][r] + bi[j];
          acc[i][j][r] = v;
          s1 += v;
          s2 += v * v;
        }
#pragma unroll
        for (int d = 1; d < 16; d <<= 1) {
          s1 += __shfl_xor(s1, d);
          s2 += __shfl_xor(s2, d);
        }
        if ((lane & 15) == 0) {
          const int rl = wm + i * 16 + ((lane >> 4) << 2) + r;
          sstat[0][w & 3][rl] = s1;
          sstat[1][w & 3][rl] = s2;
        }
      }
    }
    __syncthreads();
    const float beta_s = (MODE == 3) ? betas[lidx] : 0.f;
#pragma unroll
    for (int i = 0; i < 4; ++i) {
#pragma unroll
      for (int r = 0; r < 4; ++r) {
        const int rl = wm + i * 16 + ((lane >> 4) << 2) + r;
        const float s1 = sstat[0][0][rl] + sstat[0][1][rl] + sstat[0][2][rl] + sstat[0][3][rl];
        const float s2 = sstat[1][0][rl] + sstat[1][1][rl] + sstat[1][2][rl] + sstat[1][3][rl];
        const float mu = s1 * (1.f / 256.f);
        const float var = s2 * (1.f / 256.f) - mu * mu;
        const float rs = rsqrtf(var + 1e-5f);
        const int gm = m0 + rl;
        if (gm < M) {
          const size_t base = (size_t)gm * 256 + wn + (lane & 15);
#pragma unroll
          for (int j = 0; j < 4; ++j) {
            const float y = (acc[i][j][r] - mu) * rs * gv[j] + bv[j];
            const size_t o = base + j * 16;
            C[o] = y;
            if (MODE == 1) ZH[o] = f2bf(y);
            if (MODE == 3) outp[o] = outp[o] + beta_s * y;
          }
        }
      }
    }
  } else {
    const float beta_s = (MODE == 4) ? betas[lidx] : 0.f;
#pragma unroll
    for (int i = 0; i < 4; ++i) {
      const int gm0 = m0 + wm + i * 16 + ((lane >> 4) << 2);
#pragma unroll
      for (int r = 0; r < 4; ++r) {
        const int gm = gm0 + r;
        if (gm < M) {
          const size_t base = (size_t)gm * 256 + wn + (lane & 15);
#pragma unroll
          for (int j = 0; j < 4; ++j) {
            float v = acc[i][j][r] + bi[j];
            if (ADDZ) v += Z[base + j * 16];
            if (RELU) v = fmaxf(v, 0.f);
            C[base + j * 16] = v;
            if (MODE == 2) ZH[base + j * 16] = f2bf(v);
            if (MODE == 4) outp[base + j * 16] = beta_s * v;
          }
        }
      }
    }
  }
}

// ---------------------------------------------------------------------------
// Final mix: out[i] = sum_l betas[l] * bf2f(zhist[l][i]), 8 elems/thread
// ---------------------------------------------------------------------------
__global__ __launch_bounds__(256) void mix_kernel(
    const ushort* __restrict__ zh, const float* __restrict__ betas,
    float* __restrict__ outp, int total8, size_t stride) {
  const int i = blockIdx.x * 256 + threadIdx.x;
  if (i >= total8) return;
  float a[8] = {};
#pragma unroll
  for (int l = 0; l < NLAYER + 1; ++l) {
    const float bl = betas[l];
    const uint4 u = ((const uint4*)(zh + l * stride))[i];
    const uint32_t ww[4] = {u.x, u.y, u.z, u.w};
#pragma unroll
    for (int k = 0; k < 4; ++k) {
      union { uint32_t u; float f; } lo, hi;
      lo.u = ww[k] << 16;
      hi.u = ww[k] & 0xffff0000u;
      a[2 * k] += bl * lo.f;
      a[2 * k + 1] += bl * hi.f;
    }
  }
  f32x4 o0 = {a[0], a[1], a[2], a[3]};
  f32x4 o1 = {a[4], a[5], a[6], a[7]};
  ((f32x4*)outp)[(size_t)i * 2] = o0;
  ((f32x4*)outp)[(size_t)i * 2 + 1] = o1;
}

// ---------------------------------------------------------------------------
// CSR build (parallel scan)
// ---------------------------------------------------------------------------
__global__ void count_kernel(const int* __restrict__ dstv, int* __restrict__ deg, int E) {
  int i = blockIdx.x * 256 + threadIdx.x;
  if (i < E) atomicAdd(&deg[dstv[i]], 1);
}

__global__ void scanA_kernel(const int* __restrict__ deg, int* __restrict__ excl,
                             int* __restrict__ bsum, int n) {
  __shared__ int sm[256];
  const int i = blockIdx.x * 256 + threadIdx.x;
  const int v = (i < n) ? deg[i] : 0;
  sm[threadIdx.x] = v;
  __syncthreads();
  for (int off = 1; off < 256; off <<= 1) {
    int t = (threadIdx.x >= off) ? sm[threadIdx.x - off] : 0;
    __syncthreads();
    sm[threadIdx.x] += t;
    __syncthreads();
  }
  if (i < n) excl[i] = sm[threadIdx.x] - v;
  if (threadIdx.x == 255) bsum[blockIdx.x] = sm[255];
}

__global__ void scanB_kernel(const int* __restrict__ bsum, int* __restrict__ boff, int nb) {
  __shared__ int sm[256];
  const int v = (threadIdx.x < nb) ? bsum[threadIdx.x] : 0;
  sm[threadIdx.x] = v;
  __syncthreads();
  for (int off = 1; off < 256; off <<= 1) {
    int t = (threadIdx.x >= off) ? sm[threadIdx.x - off] : 0;
    __syncthreads();
    sm[threadIdx.x] += t;
    __syncthreads();
  }
  if (threadIdx.x < nb) boff[threadIdx.x] = sm[threadIdx.x] - v;
}

__global__ void scanC_kernel(const int* __restrict__ deg, const int* __restrict__ excl,
                             const int* __restrict__ boff, int* __restrict__ rowptr,
                             int* __restrict__ fillptr, float* __restrict__ invc,
                             int n, int E) {
  const int i = blockIdx.x * 256 + threadIdx.x;
  if (i < n) {
    const int r = excl[i] + boff[blockIdx.x];
    rowptr[i] = r;
    fillptr[i] = r;
    invc[i] = 1.0f / (float)(deg[i] + 1);
  }
  if (i == 0) rowptr[n] = E;
}

__global__ void fill_kernel(const int* __restrict__ srcv, const int* __restrict__ dstv,
                            int* __restrict__ fillptr, int* __restrict__ colv, int E) {
  int i = blockIdx.x * 256 + threadIdx.x;
  if (i < E) {
    int p = atomicAdd(&fillptr[dstv[i]], 1);
    colv[p] = srcv[i];
  }
}

// ---------------------------------------------------------------------------
// 128-d aggregation over bf16 T: s[v] = (T[v] + sum_edges T[src]) * invc[v]
// ---------------------------------------------------------------------------
__global__ __launch_bounds__(256) void agg128_kernel(
    const uint32_t* __restrict__ T, const int* __restrict__ rowptr,
    const int* __restrict__ colv, const float* __restrict__ invc,
    float* __restrict__ sout, int n) {
  const int node = blockIdx.x * 4 + (threadIdx.x >> 6);
  if (node >= n) return;
  const int lane = threadIdx.x & 63;
  auto up0 = [](uint32_t u) {
    union { uint32_t u; float f; } a; a.u = u << 16; return a.f;
  };
  auto up1 = [](uint32_t u) {
    union { uint32_t u; float f; } a; a.u = u & 0xffff0000u; return a.f;
  };
  uint32_t self = T[(size_t)node * 64 + lane];
  float a0 = up0(self), a1 = up1(self);
  float b0 = 0.f, b1 = 0.f;
  const int s = rowptr[node];
  const int e = rowptr[node + 1];
  int i = s;
  for (; i + 1 < e; i += 2) {
    const int s0 = colv[i];
    const int s1i = colv[i + 1];
    const uint32_t u0 = T[(size_t)s0 * 64 + lane];
    const uint32_t u1 = T[(size_t)s1i * 64 + lane];
    a0 += up0(u0); a1 += up1(u0);
    b0 += up0(u1); b1 += up1(u1);
  }
  if (i < e) {
    const uint32_t u0 = T[(size_t)colv[i] * 64 + lane];
    a0 += up0(u0); a1 += up1(u0);
  }
  const float ic = invc[node];
  f32x2 r;
  r[0] = (a0 + b0) * ic;
  r[1] = (a1 + b1) * ic;
  ((f32x2*)sout)[(size_t)node * 64 + lane] = r;
}

__global__ void beta_kernel(const float* __restrict__ beta, float* __restrict__ betas) {
  if (threadIdx.x == 0) {
    float mx = beta[0];
    for (int i = 1; i < NLAYER + 1; ++i) mx = fmaxf(mx, beta[i]);
    float e[NLAYER + 1];
    float s = 0.f;
    for (int i = 0; i < NLAYER + 1; ++i) {
      e[i] = expf(beta[i] - mx);
      s += e[i];
    }
    const float inv = 1.f / s;
    for (int i = 0; i < NLAYER + 1; ++i) betas[i] = e[i] * inv;
  }
}

// W[K][N] f32 -> Wt_hi[N][K], Wt_lo[N][K] bf16 (output-index coalesced)
__global__ void wconv_kernel(const float* __restrict__ W, ushort* __restrict__ Wh,
                             ushort* __restrict__ Wl, int K, int Nn) {
  const size_t matoff = (size_t)blockIdx.z * K * Nn;
  const int o = blockIdx.x * 256 + threadIdx.x;
  if (o >= K * Nn) return;
  const int nn = o / K;
  const int kk = o - nn * K;
  const float v = W[matoff + (size_t)kk * Nn + nn];
  const ushort hh = f2bf(v);
  Wh[matoff + o] = hh;
  Wl[matoff + o] = f2bf(v - bf2f(hh));
}

// ---------------------------------------------------------------------------
extern "C" void kernel_launch(void* const* d_in, const int* in_sizes, int n_in,
                              void* d_out, int out_size, void* d_ws, size_t ws_size,
                              hipStream_t stream) {
  const float* x = (const float*)d_in[0];
  const int* eidx = (const int*)d_in[1];
  const float* Win = (const float*)d_in[2];
  const float* bin_ = (const float*)d_in[3];
  const float* W1 = (const float*)d_in[4];
  const float* b1 = (const float*)d_in[5];
  const float* W2 = (const float*)d_in[6];
  const float* b2 = (const float*)d_in[7];
  const float* U1 = (const float*)d_in[8];
  const float* c1 = (const float*)d_in[9];
  const float* U2 = (const float*)d_in[10];
  const float* c2 = (const float*)d_in[11];
  const float* ln_g = (const float*)d_in[12];
  const float* ln_b = (const float*)d_in[13];
  const float* beta = (const float*)d_in[14];
  float* outp = (float*)d_out;

  const int Nn = in_sizes[0] / 128;  // 50000
  const int E = in_sizes[1] / 2;     // 800000
  const int* srcv = eidx;
  const int* dstv = eidx + E;

  char* p = (char*)d_ws;
  auto alloc = [&](size_t bytes) {
    char* r = p;
    p += (bytes + 255) & ~(size_t)255;
    return r;
  };
  float* z = (float*)alloc((size_t)Nn * HIDC * 4);
  float* hbuf = (float*)alloc((size_t)Nn * HIDC * 4);
  float* R = (float*)alloc((size_t)Nn * HIDC * 4);  // T128(bf16) | s128, also O256
  ushort* WinTh = (ushort*)alloc(128 * 256 * 2);
  ushort* WinTl = (ushort*)alloc(128 * 256 * 2);
  ushort* W1Th = (ushort*)alloc((size_t)NLAYER * 256 * 128 * 2);
  ushort* W1Tl = (ushort*)alloc((size_t)NLAYER * 256 * 128 * 2);
  ushort* W2Th = (ushort*)alloc((size_t)NLAYER * 128 * 256 * 2);
  ushort* W2Tl = (ushort*)alloc((size_t)NLAYER * 128 * 256 * 2);
  ushort* U1Th = (ushort*)alloc((size_t)NLAYER * 256 * 256 * 2);
  ushort* U1Tl = (ushort*)alloc((size_t)NLAYER * 256 * 256 * 2);
  ushort* U2Th = (ushort*)alloc((size_t)NLAYER * 256 * 256 * 2);
  ushort* U2Tl = (ushort*)alloc((size_t)NLAYER * 256 * 256 * 2);
  int* deg = (int*)alloc((size_t)Nn * 4);
  int* rowptr = (int*)alloc((size_t)(Nn + 1) * 4);
  int* fillptr = (int*)alloc((size_t)Nn * 4);
  float* invc = (float*)alloc((size_t)Nn * 4);
  int* colv = (int*)alloc((size_t)E * 4);
  int* excl = (int*)alloc((size_t)Nn * 4);
  int* bsum = (int*)alloc(256 * 4);
  int* boff = (int*)alloc(256 * 4);
  float* betas = (float*)alloc(64);

  // zhist allocated LAST, only if the workspace can hold it.
  const size_t ZS = (size_t)Nn * HIDC;
  const size_t zhist_bytes = (size_t)(NLAYER + 1) * ZS * 2;
  const size_t used = (size_t)(p - (char*)d_ws);
  const bool use_zhist = (used + zhist_bytes + 4096 <= ws_size);
  ushort* zhist = use_zhist ? (ushort*)alloc(zhist_bytes) : nullptr;

  ushort* T128 = (ushort*)R;                                 // [Nn x 128] bf16
  float* s128 = (float*)((char*)R + (size_t)Nn * MSGC * 2);  // [Nn x 128] f32
  float* Obuf = R;                                           // [Nn x 256] f32 (reuse)

  const int nscan = (Nn + 255) / 256;

  hipMemsetAsync(deg, 0, (size_t)Nn * 4, stream);
  count_kernel<<<(E + 255) / 256, 256, 0, stream>>>(dstv, deg, E);
  scanA_kernel<<<nscan, 256, 0, stream>>>(deg, excl, bsum, Nn);
  scanB_kernel<<<1, 256, 0, stream>>>(bsum, boff, nscan);
  scanC_kernel<<<nscan, 256, 0, stream>>>(deg, excl, boff, rowptr, fillptr, invc, Nn, E);
  fill_kernel<<<(E + 255) / 256, 256, 0, stream>>>(srcv, dstv, fillptr, colv, E);
  beta_kernel<<<1, 64, 0, stream>>>(beta, betas);
  wconv_kernel<<<dim3(128, 1, 1), 256, 0, stream>>>(Win, WinTh, WinTl, 128, 256);
  wconv_kernel<<<dim3(128, 1, NLAYER), 256, 0, stream>>>(W1, W1Th, W1Tl, 256, 128);
  wconv_kernel<<<dim3(128, 1, NLAYER), 256, 0, stream>>>(W2, W2Th, W2Tl, 128, 256);
  wconv_kernel<<<dim3(256, 1, NLAYER), 256, 0, stream>>>(U1, U1Th, U1Tl, 256, 256);
  wconv_kernel<<<dim3(256, 1, NLAYER), 256, 0, stream>>>(U2, U2Th, U2Tl, 256, 256);

  const int mb128 = (Nn + 127) / 128;
  const int nwave = (Nn + 3) / 4;

  // z0 = x @ Win + bin
  if (use_zhist) {
    gemm_big<0, 0, 2><<<mb128, 512, 0, stream>>>(x, WinTh, WinTl, bin_, nullptr, z,
                                                 nullptr, nullptr, zhist, betas, 0,
                                                 nullptr, Nn, 128);
  } else {
    gemm_big<0, 0, 4><<<mb128, 512, 0, stream>>>(x, WinTh, WinTl, bin_, nullptr, z,
                                                 nullptr, nullptr, nullptr, betas, 0,
                                                 outp, Nn, 128);
  }

  for (int l = 0; l < NLAYER; ++l) {
    // T128(bf16) = relu(z @ W1 + b1)   [N x 128]
    gemm_hilo<1, 1><<<dim3(mb128, 1), 256, 0, stream>>>(
        z, W1Th + (size_t)l * 256 * 128, W1Tl + (size_t)l * 256 * 128, b1 + l * 128,
        (float*)T128, Nn, 256, 128);
    // s128 = segmean(T128)
    agg128_kernel<<<nwave, 256, 0, stream>>>((const uint32_t*)T128, rowptr, colv, invc,
                                             s128, Nn);
    // h = z + s128 @ W2 + b2     [N x 256]
    gemm_big<0, 1, 0><<<mb128, 512, 0, stream>>>(
        s128, W2Th + (size_t)l * 128 * 256, W2Tl + (size_t)l * 128 * 256, b2 + l * 256,
        z, hbuf, nullptr, nullptr, nullptr, nullptr, 0, nullptr, Nn, 128);
    // O = relu(h @ U1 + c1)      [N x 256]
    gemm_big<1, 0, 0><<<mb128, 512, 0, stream>>>(
        hbuf, U1Th + (size_t)l * 256 * 256, U1Tl + (size_t)l * 256 * 256, c1 + l * 256,
        nullptr, Obuf, nullptr, nullptr, nullptr, nullptr, 0, nullptr, Nn, 256);
    // z = LN(O @ U2 + c2)*g+b ; accumulate output
    if (use_zhist) {
      gemm_big<0, 0, 1><<<mb128, 512, 0, stream>>>(
          Obuf, U2Th + (size_t)l * 256 * 256, U2Tl + (size_t)l * 256 * 256, c2 + l * 256,
          nullptr, z, ln_g + l * 256, ln_b + l * 256, zhist + (size_t)(l + 1) * ZS,
          betas, l + 1, nullptr, Nn, 256);
    } else {
      gemm_big<0, 0, 3><<<mb128, 512, 0, stream>>>(
          Obuf, U2Th + (size_t)l * 256 * 256, U2Tl + (size_t)l * 256 * 256, c2 + l * 256,
          nullptr, z, ln_g + l * 256, ln_b + l * 256, nullptr, betas, l + 1, outp, Nn, 256);
    }
  }

  if (use_zhist) {
    const int total8 = (Nn * HIDC) / 8;
    mix_kernel<<<(total8 + 255) / 256, 256, 0, stream>>>(zhist, betas, outp, total8, ZS);
  }
}

// Round 7
// 1615.574 us; speedup vs baseline: 1.9055x; 1.1626x over previous
//
#include <hip/hip_runtime.h>
#include <stdint.h>

typedef __attribute__((ext_vector_type(4))) float f32x4;
typedef __attribute__((ext_vector_type(2))) float f32x2;
typedef __attribute__((ext_vector_type(8))) short bf16x8;

#define HIDC 256
#define MSGC 128
#define NLAYER 10

__device__ __forceinline__ ushort f2bf(float f) {
  union { float f; uint32_t u; } a; a.f = f;
  uint32_t u = a.u;
  return (ushort)((u + 0x7fffu + ((u >> 16) & 1u)) >> 16);
}
__device__ __forceinline__ float bf2f(ushort h) {
  union { float f; uint32_t u; } a; a.u = ((uint32_t)h) << 16;
  return a.f;
}

// ---------------------------------------------------------------------------
// W1 GEMM: A bf16 [M x 256], B hi/lo [128 x 256], C bf16 [M x 128].
// Tile 128x128, 4 waves, BK=64. RELU fused.
// ---------------------------------------------------------------------------
__global__ __launch_bounds__(256, 2) void gemm_w1(
    const ushort* __restrict__ A, const ushort* __restrict__ Bh,
    const ushort* __restrict__ Bl, const float* __restrict__ bias,
    ushort* __restrict__ C, int M) {
  __shared__ ushort lA[128 * 64];
  __shared__ ushort lBh[128 * 64];
  __shared__ ushort lBl[128 * 64];
  const int tid = threadIdx.x;
  const int m0 = blockIdx.x * 128;
  const int lane = tid & 63;
  const int w = tid >> 6;
  const int wm = (w >> 1) * 64;
  const int wn = (w & 1) * 64;
  const int rr = tid >> 3;  // 0..31
  const int cc = tid & 7;   // 0..7
  f32x4 acc[4][4] = {};

#pragma unroll
  for (int s = 0; s < 4; ++s) {  // K = 256, BK = 64
    const int k0 = s * 64;
#pragma unroll
    for (int p = 0; p < 4; ++p) {
      const int row = p * 32 + rr;
      const int gm = m0 + row;
      bf16x8 av = {0, 0, 0, 0, 0, 0, 0, 0};
      if (gm < M) av = *(const bf16x8*)(A + (size_t)gm * 256 + k0 + cc * 8);
      const uint32_t off = (uint32_t)((row * 128 + cc * 16) ^ ((row & 7) << 4));
      *(bf16x8*)((char*)lA + off) = av;
    }
#pragma unroll
    for (int p = 0; p < 4; ++p) {
      const int row = p * 32 + rr;
      const size_t gb = (size_t)row * 256 + k0 + cc * 8;
      bf16x8 bh = *(const bf16x8*)(Bh + gb);
      bf16x8 bl = *(const bf16x8*)(Bl + gb);
      const uint32_t off = (uint32_t)((row * 128 + cc * 16) ^ ((row & 7) << 4));
      *(bf16x8*)((char*)lBh + off) = bh;
      *(bf16x8*)((char*)lBl + off) = bl;
    }
    __syncthreads();
#pragma unroll
    for (int kk = 0; kk < 2; ++kk) {
      bf16x8 ah[4];
#pragma unroll
      for (int i = 0; i < 4; ++i) {
        const int arow = wm + i * 16 + (lane & 15);
        const uint32_t ao =
            (uint32_t)((arow * 128 + kk * 64 + ((lane >> 4) * 16)) ^ ((arow & 7) << 4));
        ah[i] = *(const bf16x8*)((const char*)lA + ao);
      }
#pragma unroll
      for (int j = 0; j < 4; ++j) {
        const int brow = wn + j * 16 + (lane & 15);
        const uint32_t bo =
            (uint32_t)((brow * 128 + kk * 64 + ((lane >> 4) * 16)) ^ ((brow & 7) << 4));
        const bf16x8 bh = *(const bf16x8*)((const char*)lBh + bo);
        const bf16x8 bl = *(const bf16x8*)((const char*)lBl + bo);
#pragma unroll
        for (int i = 0; i < 4; ++i) {
          acc[i][j] = __builtin_amdgcn_mfma_f32_16x16x32_bf16(ah[i], bh, acc[i][j], 0, 0, 0);
          acc[i][j] = __builtin_amdgcn_mfma_f32_16x16x32_bf16(ah[i], bl, acc[i][j], 0, 0, 0);
        }
      }
    }
    __syncthreads();
  }
  float bi[4];
#pragma unroll
  for (int j = 0; j < 4; ++j) bi[j] = bias[wn + j * 16 + (lane & 15)];
#pragma unroll
  for (int i = 0; i < 4; ++i) {
    const int gm0 = m0 + wm + i * 16 + ((lane >> 4) << 2);
#pragma unroll
    for (int r = 0; r < 4; ++r) {
      const int gm = gm0 + r;
      if (gm < M) {
        const size_t base = (size_t)gm * 128 + wn + (lane & 15);
#pragma unroll
        for (int j = 0; j < 4; ++j) {
          C[base + j * 16] = f2bf(fmaxf(acc[i][j][r] + bi[j], 0.f));
        }
      }
    }
  }
}

// ---------------------------------------------------------------------------
// Big GEMM: tile 128x256, 8 waves, BK=32, N fixed = 256. C is bf16.
// ABF16: A is bf16 (single LDS buf, 2 MFMA) else fp32 hi/lo split (3 MFMA).
// ADDZ: v += bf2f(Z) before store (residual).
// MODE 0: C = bf16(act(v))
// MODE 1: y = LN(v)*g+b_; C = bf16(y)                     (zhist path)
// MODE 3: y = LN(v)*g+b_; C = bf16(y); outp += betas[lidx]*y
// MODE 4: C = bf16(v); outp = betas[lidx]*v               (z0 fallback)
// ---------------------------------------------------------------------------
template <int ABF16, int RELU, int ADDZ, int MODE>
__global__ __launch_bounds__(512, 4) void gemm_big(
    const void* __restrict__ Aptr, const ushort* __restrict__ Bh,
    const ushort* __restrict__ Bl, const float* __restrict__ bias,
    const ushort* __restrict__ Z, ushort* __restrict__ C,
    const float* __restrict__ g, const float* __restrict__ b_,
    const float* __restrict__ betas, int lidx, float* __restrict__ outp,
    int M, int K) {
  __shared__ ushort lAh[128 * 32];
  __shared__ ushort lAl[128 * 32];
  __shared__ ushort lBh[256 * 32];
  __shared__ ushort lBl[256 * 32];
  __shared__ float sstat[2][4][128];
  const float* Af = (const float*)Aptr;
  const ushort* Ab = (const ushort*)Aptr;
  const int tid = threadIdx.x;
  const int m0 = blockIdx.x * 128;
  const int lane = tid & 63;
  const int w = tid >> 6;        // 0..7
  const int wm = (w >> 2) * 64;  // 0,64
  const int wn = (w & 3) * 64;   // 0,64,128,192
  const int srow = tid >> 2;     // 0..127
  const int cc = tid & 3;        // 0..3
  f32x4 acc[4][4] = {};

  const int nsteps = K >> 5;
  for (int s = 0; s < nsteps; ++s) {
    const int k0 = s * 32;
    // ---- stage A
    if (ABF16) {
      const int gm = m0 + srow;
      bf16x8 av = {0, 0, 0, 0, 0, 0, 0, 0};
      if (gm < M) av = *(const bf16x8*)(Ab + (size_t)gm * K + k0 + cc * 8);
      const uint32_t off = (uint32_t)((srow * 64 + cc * 16) ^ ((srow & 6) << 3));
      *(bf16x8*)((char*)lAh + off) = av;
    } else {
      const int gm = m0 + srow;
      f32x4 va = {0.f, 0.f, 0.f, 0.f}, vb = {0.f, 0.f, 0.f, 0.f};
      if (gm < M) {
        const float* ga = Af + (size_t)gm * K + k0 + cc * 8;
        va = *(const f32x4*)ga;
        vb = *(const f32x4*)(ga + 4);
      }
      bf16x8 hv, lv;
#pragma unroll
      for (int e = 0; e < 4; ++e) {
        float v = va[e];
        ushort hh = f2bf(v);
        hv[e] = (short)hh;
        lv[e] = (short)f2bf(v - bf2f(hh));
        float v2 = vb[e];
        ushort hh2 = f2bf(v2);
        hv[e + 4] = (short)hh2;
        lv[e + 4] = (short)f2bf(v2 - bf2f(hh2));
      }
      const uint32_t off = (uint32_t)((srow * 64 + cc * 16) ^ ((srow & 6) << 3));
      *(bf16x8*)((char*)lAh + off) = hv;
      *(bf16x8*)((char*)lAl + off) = lv;
    }
    // ---- stage B: 256 rows x 32 bf16 hi/lo, 2 passes of 128 rows
#pragma unroll
    for (int p = 0; p < 2; ++p) {
      const int brow = p * 128 + srow;
      const size_t gb = (size_t)brow * K + k0 + cc * 8;
      bf16x8 bh = *(const bf16x8*)(Bh + gb);
      bf16x8 bl = *(const bf16x8*)(Bl + gb);
      const uint32_t off = (uint32_t)((brow * 64 + cc * 16) ^ ((brow & 6) << 3));
      *(bf16x8*)((char*)lBh + off) = bh;
      *(bf16x8*)((char*)lBl + off) = bl;
    }
    __syncthreads();
    // ---- compute
    {
      bf16x8 ah[4], al[4];
#pragma unroll
      for (int i = 0; i < 4; ++i) {
        const int arow = wm + i * 16 + (lane & 15);
        const uint32_t ao =
            (uint32_t)((arow * 64 + ((lane >> 4) * 16)) ^ ((arow & 6) << 3));
        ah[i] = *(const bf16x8*)((const char*)lAh + ao);
        if (!ABF16) al[i] = *(const bf16x8*)((const char*)lAl + ao);
      }
#pragma unroll
      for (int j = 0; j < 4; ++j) {
        const int brow = wn + j * 16 + (lane & 15);
        const uint32_t bo =
            (uint32_t)((brow * 64 + ((lane >> 4) * 16)) ^ ((brow & 6) << 3));
        const bf16x8 bh = *(const bf16x8*)((const char*)lBh + bo);
        const bf16x8 bl = *(const bf16x8*)((const char*)lBl + bo);
#pragma unroll
        for (int i = 0; i < 4; ++i) {
          acc[i][j] = __builtin_amdgcn_mfma_f32_16x16x32_bf16(ah[i], bh, acc[i][j], 0, 0, 0);
          acc[i][j] = __builtin_amdgcn_mfma_f32_16x16x32_bf16(ah[i], bl, acc[i][j], 0, 0, 0);
          if (!ABF16)
            acc[i][j] = __builtin_amdgcn_mfma_f32_16x16x32_bf16(al[i], bh, acc[i][j], 0, 0, 0);
        }
      }
    }
    __syncthreads();
  }

  // ---- epilogue: frag row = wm + i*16 + (lane>>4)*4 + r, col = wn + j*16 + (lane&15)
  float bi[4];
#pragma unroll
  for (int j = 0; j < 4; ++j) bi[j] = bias[wn + j * 16 + (lane & 15)];

  if (MODE == 1 || MODE == 3) {
    float gv[4], bv[4];
#pragma unroll
    for (int j = 0; j < 4; ++j) {
      gv[j] = g[wn + j * 16 + (lane & 15)];
      bv[j] = b_[wn + j * 16 + (lane & 15)];
    }
#pragma unroll
    for (int i = 0; i < 4; ++i) {
#pragma unroll
      for (int r = 0; r < 4; ++r) {
        float s1 = 0.f, s2 = 0.f;
#pragma unroll
        for (int j = 0; j < 4; ++j) {
          float v = acc[i][j][r] + bi[j];
          acc[i][j][r] = v;
          s1 += v;
          s2 += v * v;
        }
#pragma unroll
        for (int d = 1; d < 16; d <<= 1) {
          s1 += __shfl_xor(s1, d);
          s2 += __shfl_xor(s2, d);
        }
        if ((lane & 15) == 0) {
          const int rl = wm + i * 16 + ((lane >> 4) << 2) + r;
          sstat[0][w & 3][rl] = s1;
          sstat[1][w & 3][rl] = s2;
        }
      }
    }
    __syncthreads();
    const float beta_s = (MODE == 3) ? betas[lidx] : 0.f;
#pragma unroll
    for (int i = 0; i < 4; ++i) {
#pragma unroll
      for (int r = 0; r < 4; ++r) {
        const int rl = wm + i * 16 + ((lane >> 4) << 2) + r;
        const float s1 = sstat[0][0][rl] + sstat[0][1][rl] + sstat[0][2][rl] + sstat[0][3][rl];
        const float s2 = sstat[1][0][rl] + sstat[1][1][rl] + sstat[1][2][rl] + sstat[1][3][rl];
        const float mu = s1 * (1.f / 256.f);
        const float var = s2 * (1.f / 256.f) - mu * mu;
        const float rs = rsqrtf(var + 1e-5f);
        const int gm = m0 + rl;
        if (gm < M) {
          const size_t base = (size_t)gm * 256 + wn + (lane & 15);
#pragma unroll
          for (int j = 0; j < 4; ++j) {
            const float y = (acc[i][j][r] - mu) * rs * gv[j] + bv[j];
            const size_t o = base + j * 16;
            C[o] = f2bf(y);
            if (MODE == 3) outp[o] = outp[o] + beta_s * y;
          }
        }
      }
    }
  } else {
    const float beta_s = (MODE == 4) ? betas[lidx] : 0.f;
#pragma unroll
    for (int i = 0; i < 4; ++i) {
      const int gm0 = m0 + wm + i * 16 + ((lane >> 4) << 2);
#pragma unroll
      for (int r = 0; r < 4; ++r) {
        const int gm = gm0 + r;
        if (gm < M) {
          const size_t base = (size_t)gm * 256 + wn + (lane & 15);
#pragma unroll
          for (int j = 0; j < 4; ++j) {
            float v = acc[i][j][r] + bi[j];
            if (ADDZ) v += bf2f(Z[base + j * 16]);
            if (RELU) v = fmaxf(v, 0.f);
            C[base + j * 16] = f2bf(v);
            if (MODE == 4) outp[base + j * 16] = beta_s * v;
          }
        }
      }
    }
  }
}

// ---------------------------------------------------------------------------
// Final mix: out[i] = sum_l betas[l] * bf2f(zhist[l][i]), 8 elems/thread
// ---------------------------------------------------------------------------
__global__ __launch_bounds__(256) void mix_kernel(
    const ushort* __restrict__ zh, const float* __restrict__ betas,
    float* __restrict__ outp, int total8, size_t stride) {
  const int i = blockIdx.x * 256 + threadIdx.x;
  if (i >= total8) return;
  float a[8] = {};
#pragma unroll
  for (int l = 0; l < NLAYER + 1; ++l) {
    const float bl = betas[l];
    const uint4 u = ((const uint4*)(zh + l * stride))[i];
    const uint32_t ww[4] = {u.x, u.y, u.z, u.w};
#pragma unroll
    for (int k = 0; k < 4; ++k) {
      union { uint32_t u; float f; } lo, hi;
      lo.u = ww[k] << 16;
      hi.u = ww[k] & 0xffff0000u;
      a[2 * k] += bl * lo.f;
      a[2 * k + 1] += bl * hi.f;
    }
  }
  f32x4 o0 = {a[0], a[1], a[2], a[3]};
  f32x4 o1 = {a[4], a[5], a[6], a[7]};
  ((f32x4*)outp)[(size_t)i * 2] = o0;
  ((f32x4*)outp)[(size_t)i * 2 + 1] = o1;
}

// ---------------------------------------------------------------------------
// CSR build (parallel scan)
// ---------------------------------------------------------------------------
__global__ void count_kernel(const int* __restrict__ dstv, int* __restrict__ deg, int E) {
  int i = blockIdx.x * 256 + threadIdx.x;
  if (i < E) atomicAdd(&deg[dstv[i]], 1);
}

__global__ void scanA_kernel(const int* __restrict__ deg, int* __restrict__ excl,
                             int* __restrict__ bsum, int n) {
  __shared__ int sm[256];
  const int i = blockIdx.x * 256 + threadIdx.x;
  const int v = (i < n) ? deg[i] : 0;
  sm[threadIdx.x] = v;
  __syncthreads();
  for (int off = 1; off < 256; off <<= 1) {
    int t = (threadIdx.x >= off) ? sm[threadIdx.x - off] : 0;
    __syncthreads();
    sm[threadIdx.x] += t;
    __syncthreads();
  }
  if (i < n) excl[i] = sm[threadIdx.x] - v;
  if (threadIdx.x == 255) bsum[blockIdx.x] = sm[255];
}

__global__ void scanB_kernel(const int* __restrict__ bsum, int* __restrict__ boff, int nb) {
  __shared__ int sm[256];
  const int v = (threadIdx.x < nb) ? bsum[threadIdx.x] : 0;
  sm[threadIdx.x] = v;
  __syncthreads();
  for (int off = 1; off < 256; off <<= 1) {
    int t = (threadIdx.x >= off) ? sm[threadIdx.x - off] : 0;
    __syncthreads();
    sm[threadIdx.x] += t;
    __syncthreads();
  }
  if (threadIdx.x < nb) boff[threadIdx.x] = sm[threadIdx.x] - v;
}

__global__ void scanC_kernel(const int* __restrict__ deg, const int* __restrict__ excl,
                             const int* __restrict__ boff, int* __restrict__ rowptr,
                             int* __restrict__ fillptr, float* __restrict__ invc,
                             int n, int E) {
  const int i = blockIdx.x * 256 + threadIdx.x;
  if (i < n) {
    const int r = excl[i] + boff[blockIdx.x];
    rowptr[i] = r;
    fillptr[i] = r;
    invc[i] = 1.0f / (float)(deg[i] + 1);
  }
  if (i == 0) rowptr[n] = E;
}

__global__ void fill_kernel(const int* __restrict__ srcv, const int* __restrict__ dstv,
                            int* __restrict__ fillptr, int* __restrict__ colv, int E) {
  int i = blockIdx.x * 256 + threadIdx.x;
  if (i < E) {
    int p = atomicAdd(&fillptr[dstv[i]], 1);
    colv[p] = srcv[i];
  }
}

// ---------------------------------------------------------------------------
// 128-d aggregation over bf16 T: s[v] = (T[v] + sum_edges T[src]) * invc[v]
// ---------------------------------------------------------------------------
__global__ __launch_bounds__(256) void agg128_kernel(
    const uint32_t* __restrict__ T, const int* __restrict__ rowptr,
    const int* __restrict__ colv, const float* __restrict__ invc,
    float* __restrict__ sout, int n) {
  const int node = blockIdx.x * 4 + (threadIdx.x >> 6);
  if (node >= n) return;
  const int lane = threadIdx.x & 63;
  auto up0 = [](uint32_t u) {
    union { uint32_t u; float f; } a; a.u = u << 16; return a.f;
  };
  auto up1 = [](uint32_t u) {
    union { uint32_t u; float f; } a; a.u = u & 0xffff0000u; return a.f;
  };
  uint32_t self = T[(size_t)node * 64 + lane];
  float a0 = up0(self), a1 = up1(self);
  float b0 = 0.f, b1 = 0.f;
  const int s = rowptr[node];
  const int e = rowptr[node + 1];
  int i = s;
  for (; i + 1 < e; i += 2) {
    const int s0 = colv[i];
    const int s1i = colv[i + 1];
    const uint32_t u0 = T[(size_t)s0 * 64 + lane];
    const uint32_t u1 = T[(size_t)s1i * 64 + lane];
    a0 += up0(u0); a1 += up1(u0);
    b0 += up0(u1); b1 += up1(u1);
  }
  if (i < e) {
    const uint32_t u0 = T[(size_t)colv[i] * 64 + lane];
    a0 += up0(u0); a1 += up1(u0);
  }
  const float ic = invc[node];
  f32x2 r;
  r[0] = (a0 + b0) * ic;
  r[1] = (a1 + b1) * ic;
  ((f32x2*)sout)[(size_t)node * 64 + lane] = r;
}

__global__ void beta_kernel(const float* __restrict__ beta, float* __restrict__ betas) {
  if (threadIdx.x == 0) {
    float mx = beta[0];
    for (int i = 1; i < NLAYER + 1; ++i) mx = fmaxf(mx, beta[i]);
    float e[NLAYER + 1];
    float s = 0.f;
    for (int i = 0; i < NLAYER + 1; ++i) {
      e[i] = expf(beta[i] - mx);
      s += e[i];
    }
    const float inv = 1.f / s;
    for (int i = 0; i < NLAYER + 1; ++i) betas[i] = e[i] * inv;
  }
}

// W[K][N] f32 -> Wt_hi[N][K], Wt_lo[N][K] bf16 (output-index coalesced)
__global__ void wconv_kernel(const float* __restrict__ W, ushort* __restrict__ Wh,
                             ushort* __restrict__ Wl, int K, int Nn) {
  const size_t matoff = (size_t)blockIdx.z * K * Nn;
  const int o = blockIdx.x * 256 + threadIdx.x;
  if (o >= K * Nn) return;
  const int nn = o / K;
  const int kk = o - nn * K;
  const float v = W[matoff + (size_t)kk * Nn + nn];
  const ushort hh = f2bf(v);
  Wh[matoff + o] = hh;
  Wl[matoff + o] = f2bf(v - bf2f(hh));
}

// ---------------------------------------------------------------------------
extern "C" void kernel_launch(void* const* d_in, const int* in_sizes, int n_in,
                              void* d_out, int out_size, void* d_ws, size_t ws_size,
                              hipStream_t stream) {
  const float* x = (const float*)d_in[0];
  const int* eidx = (const int*)d_in[1];
  const float* Win = (const float*)d_in[2];
  const float* bin_ = (const float*)d_in[3];
  const float* W1 = (const float*)d_in[4];
  const float* b1 = (const float*)d_in[5];
  const float* W2 = (const float*)d_in[6];
  const float* b2 = (const float*)d_in[7];
  const float* U1 = (const float*)d_in[8];
  const float* c1 = (const float*)d_in[9];
  const float* U2 = (const float*)d_in[10];
  const float* c2 = (const float*)d_in[11];
  const float* ln_g = (const float*)d_in[12];
  const float* ln_b = (const float*)d_in[13];
  const float* beta = (const float*)d_in[14];
  float* outp = (float*)d_out;

  const int Nn = in_sizes[0] / 128;  // 50000
  const int E = in_sizes[1] / 2;     // 800000
  const int* srcv = eidx;
  const int* dstv = eidx + E;

  char* p = (char*)d_ws;
  auto alloc = [&](size_t bytes) {
    char* r = p;
    p += (bytes + 255) & ~(size_t)255;
    return r;
  };
  ushort* hbuf = (ushort*)alloc((size_t)Nn * HIDC * 2);   // h bf16
  ushort* Obuf = (ushort*)alloc((size_t)Nn * HIDC * 2);   // O bf16
  ushort* T128 = (ushort*)alloc((size_t)Nn * MSGC * 2);   // T bf16
  float* s128 = (float*)alloc((size_t)Nn * MSGC * 4);     // s fp32
  ushort* WinTh = (ushort*)alloc(128 * 256 * 2);
  ushort* WinTl = (ushort*)alloc(128 * 256 * 2);
  ushort* W1Th = (ushort*)alloc((size_t)NLAYER * 256 * 128 * 2);
  ushort* W1Tl = (ushort*)alloc((size_t)NLAYER * 256 * 128 * 2);
  ushort* W2Th = (ushort*)alloc((size_t)NLAYER * 128 * 256 * 2);
  ushort* W2Tl = (ushort*)alloc((size_t)NLAYER * 128 * 256 * 2);
  ushort* U1Th = (ushort*)alloc((size_t)NLAYER * 256 * 256 * 2);
  ushort* U1Tl = (ushort*)alloc((size_t)NLAYER * 256 * 256 * 2);
  ushort* U2Th = (ushort*)alloc((size_t)NLAYER * 256 * 256 * 2);
  ushort* U2Tl = (ushort*)alloc((size_t)NLAYER * 256 * 256 * 2);
  int* deg = (int*)alloc((size_t)Nn * 4);
  int* rowptr = (int*)alloc((size_t)(Nn + 1) * 4);
  int* fillptr = (int*)alloc((size_t)Nn * 4);
  float* invc = (float*)alloc((size_t)Nn * 4);
  int* colv = (int*)alloc((size_t)E * 4);
  int* excl = (int*)alloc((size_t)Nn * 4);
  int* bsum = (int*)alloc(256 * 4);
  int* boff = (int*)alloc(256 * 4);
  float* betas = (float*)alloc(64);

  // z storage: zhist (all 11 layers, bf16) if workspace allows, else 1 slot.
  const size_t ZS = (size_t)Nn * HIDC;
  const size_t zhist_bytes = (size_t)(NLAYER + 1) * ZS * 2;
  const size_t used = (size_t)(p - (char*)d_ws);
  const bool use_zhist = (used + zhist_bytes + 4096 <= ws_size);
  ushort* zbase = (ushort*)alloc(use_zhist ? zhist_bytes : ZS * 2);
  auto zslot = [&](int l) { return use_zhist ? zbase + (size_t)l * ZS : zbase; };

  const int nscan = (Nn + 255) / 256;

  hipMemsetAsync(deg, 0, (size_t)Nn * 4, stream);
  count_kernel<<<(E + 255) / 256, 256, 0, stream>>>(dstv, deg, E);
  scanA_kernel<<<nscan, 256, 0, stream>>>(deg, excl, bsum, Nn);
  scanB_kernel<<<1, 256, 0, stream>>>(bsum, boff, nscan);
  scanC_kernel<<<nscan, 256, 0, stream>>>(deg, excl, boff, rowptr, fillptr, invc, Nn, E);
  fill_kernel<<<(E + 255) / 256, 256, 0, stream>>>(srcv, dstv, fillptr, colv, E);
  beta_kernel<<<1, 64, 0, stream>>>(beta, betas);
  wconv_kernel<<<dim3(128, 1, 1), 256, 0, stream>>>(Win, WinTh, WinTl, 128, 256);
  wconv_kernel<<<dim3(128, 1, NLAYER), 256, 0, stream>>>(W1, W1Th, W1Tl, 256, 128);
  wconv_kernel<<<dim3(128, 1, NLAYER), 256, 0, stream>>>(W2, W2Th, W2Tl, 128, 256);
  wconv_kernel<<<dim3(256, 1, NLAYER), 256, 0, stream>>>(U1, U1Th, U1Tl, 256, 256);
  wconv_kernel<<<dim3(256, 1, NLAYER), 256, 0, stream>>>(U2, U2Th, U2Tl, 256, 256);

  const int mb128 = (Nn + 127) / 128;
  const int nwave = (Nn + 3) / 4;

  // z0 = x @ Win + bin
  if (use_zhist) {
    gemm_big<0, 0, 0, 0><<<mb128, 512, 0, stream>>>(
        x, WinTh, WinTl, bin_, nullptr, zslot(0), nullptr, nullptr, betas, 0, nullptr,
        Nn, 128);
  } else {
    gemm_big<0, 0, 0, 4><<<mb128, 512, 0, stream>>>(
        x, WinTh, WinTl, bin_, nullptr, zslot(0), nullptr, nullptr, betas, 0, outp,
        Nn, 128);
  }

  for (int l = 0; l < NLAYER; ++l) {
    // T = bf16(relu(z @ W1 + b1))   [N x 128]
    gemm_w1<<<mb128, 256, 0, stream>>>(
        zslot(l), W1Th + (size_t)l * 256 * 128, W1Tl + (size_t)l * 256 * 128,
        b1 + l * 128, T128, Nn);
    // s = segmean(T)
    agg128_kernel<<<nwave, 256, 0, stream>>>((const uint32_t*)T128, rowptr, colv, invc,
                                             s128, Nn);
    // h = bf16(z + s @ W2 + b2)     [N x 256]
    gemm_big<0, 0, 1, 0><<<mb128, 512, 0, stream>>>(
        s128, W2Th + (size_t)l * 128 * 256, W2Tl + (size_t)l * 128 * 256, b2 + l * 256,
        zslot(l), hbuf, nullptr, nullptr, betas, 0, nullptr, Nn, 128);
    // O = bf16(relu(h @ U1 + c1))   [N x 256]
    gemm_big<1, 1, 0, 0><<<mb128, 512, 0, stream>>>(
        hbuf, U1Th + (size_t)l * 256 * 256, U1Tl + (size_t)l * 256 * 256, c1 + l * 256,
        nullptr, Obuf, nullptr, nullptr, betas, 0, nullptr, Nn, 256);
    // z_{l+1} = LN(O @ U2 + c2)*g+b
    if (use_zhist) {
      gemm_big<1, 0, 0, 1><<<mb128, 512, 0, stream>>>(
          Obuf, U2Th + (size_t)l * 256 * 256, U2Tl + (size_t)l * 256 * 256, c2 + l * 256,
          nullptr, zslot(l + 1), ln_g + l * 256, ln_b + l * 256, betas, l + 1, nullptr,
          Nn, 256);
    } else {
      gemm_big<1, 0, 0, 3><<<mb128, 512, 0, stream>>>(
          Obuf, U2Th + (size_t)l * 256 * 256, U2Tl + (size_t)l * 256 * 256, c2 + l * 256,
          nullptr, zslot(l + 1), ln_g + l * 256, ln_b + l * 256, betas, l + 1, outp,
          Nn, 256);
    }
  }

  if (use_zhist) {
    const int total8 = (Nn * HIDC) / 8;
    mix_kernel<<<(total8 + 255) / 256, 256, 0, stream>>>(zbase, betas, outp, total8, ZS);
  }
}

// Round 8
// 1464.281 us; speedup vs baseline: 2.1024x; 1.1033x over previous
//
#include <hip/hip_runtime.h>
#include <stdint.h>

typedef __attribute__((ext_vector_type(4))) float f32x4;
typedef __attribute__((ext_vector_type(8))) short bf16x8;

#define HIDC 256
#define MSGC 128
#define NLAYER 10

__device__ __forceinline__ ushort f2bf(float f) {
  union { float f; uint32_t u; } a; a.f = f;
  uint32_t u = a.u;
  return (ushort)((u + 0x7fffu + ((u >> 16) & 1u)) >> 16);
}
__device__ __forceinline__ float bf2f(ushort h) {
  union { float f; uint32_t u; } a; a.u = ((uint32_t)h) << 16;
  return a.f;
}

// ---------------------------------------------------------------------------
// W1 GEMM: A bf16 [M x 256], B bf16 [128 x 256](transposed), C bf16 [M x 128].
// Tile 128x128, 4 waves, BK=64, RELU fused. 32 KB LDS -> 4 blocks/CU.
// ---------------------------------------------------------------------------
__global__ __launch_bounds__(256, 4) void gemm_w1(
    const ushort* __restrict__ A, const ushort* __restrict__ B,
    const float* __restrict__ bias, ushort* __restrict__ C, int M) {
  __shared__ ushort lA[128 * 64];
  __shared__ ushort lB[128 * 64];
  const int tid = threadIdx.x;
  const int m0 = blockIdx.x * 128;
  const int lane = tid & 63;
  const int w = tid >> 6;
  const int wm = (w >> 1) * 64;
  const int wn = (w & 1) * 64;
  const int rr = tid >> 3;  // 0..31
  const int cc = tid & 7;   // 0..7
  f32x4 acc[4][4] = {};

#pragma unroll
  for (int s = 0; s < 4; ++s) {  // K = 256
    const int k0 = s * 64;
#pragma unroll
    for (int p = 0; p < 4; ++p) {
      const int row = p * 32 + rr;
      const int gm = m0 + row;
      bf16x8 av = {0, 0, 0, 0, 0, 0, 0, 0};
      if (gm < M) av = *(const bf16x8*)(A + (size_t)gm * 256 + k0 + cc * 8);
      const uint32_t off = (uint32_t)((row * 128 + cc * 16) ^ ((row & 7) << 4));
      *(bf16x8*)((char*)lA + off) = av;
    }
#pragma unroll
    for (int p = 0; p < 4; ++p) {
      const int row = p * 32 + rr;
      bf16x8 bv = *(const bf16x8*)(B + (size_t)row * 256 + k0 + cc * 8);
      const uint32_t off = (uint32_t)((row * 128 + cc * 16) ^ ((row & 7) << 4));
      *(bf16x8*)((char*)lB + off) = bv;
    }
    __syncthreads();
#pragma unroll
    for (int kk = 0; kk < 2; ++kk) {
      bf16x8 ah[4];
#pragma unroll
      for (int i = 0; i < 4; ++i) {
        const int arow = wm + i * 16 + (lane & 15);
        const uint32_t ao =
            (uint32_t)((arow * 128 + kk * 64 + ((lane >> 4) * 16)) ^ ((arow & 7) << 4));
        ah[i] = *(const bf16x8*)((const char*)lA + ao);
      }
#pragma unroll
      for (int j = 0; j < 4; ++j) {
        const int brow = wn + j * 16 + (lane & 15);
        const uint32_t bo =
            (uint32_t)((brow * 128 + kk * 64 + ((lane >> 4) * 16)) ^ ((brow & 7) << 4));
        const bf16x8 bv = *(const bf16x8*)((const char*)lB + bo);
#pragma unroll
        for (int i = 0; i < 4; ++i)
          acc[i][j] = __builtin_amdgcn_mfma_f32_16x16x32_bf16(ah[i], bv, acc[i][j], 0, 0, 0);
      }
    }
    __syncthreads();
  }
  float bi[4];
#pragma unroll
  for (int j = 0; j < 4; ++j) bi[j] = bias[wn + j * 16 + (lane & 15)];
#pragma unroll
  for (int i = 0; i < 4; ++i) {
    const int gm0 = m0 + wm + i * 16 + ((lane >> 4) << 2);
#pragma unroll
    for (int r = 0; r < 4; ++r) {
      const int gm = gm0 + r;
      if (gm < M) {
        const size_t base = (size_t)gm * 128 + wn + (lane & 15);
#pragma unroll
        for (int j = 0; j < 4; ++j)
          C[base + j * 16] = f2bf(fmaxf(acc[i][j][r] + bi[j], 0.f));
      }
    }
  }
}

// ---------------------------------------------------------------------------
// Big GEMM: A bf16 [M x K], B bf16 [256 x K], tile 128x256, 8 waves, BK=64.
// LDS 52 KB -> 2 blocks/CU. C bf16.
// LN=0: C = bf16(act(A@B^T + bias [+Z]))
// LN=1: C = bf16(LN(A@B^T + bias)*g + b_)
// ---------------------------------------------------------------------------
template <int RELU, int ADDZ, int LN>
__global__ __launch_bounds__(512, 4) void gemm_big(
    const ushort* __restrict__ A, const ushort* __restrict__ B,
    const float* __restrict__ bias, const ushort* __restrict__ Z,
    ushort* __restrict__ C, const float* __restrict__ g,
    const float* __restrict__ b_, int M, int K) {
  __shared__ ushort lA[128 * 64];
  __shared__ ushort lB[256 * 64];
  __shared__ float sstat[2][4][128];
  const int tid = threadIdx.x;
  const int m0 = blockIdx.x * 128;
  const int lane = tid & 63;
  const int w = tid >> 6;        // 0..7
  const int wm = (w >> 2) * 64;  // 0,64
  const int wn = (w & 3) * 64;   // 0,64,128,192
  const int rr = tid >> 3;       // 0..63
  const int cc = tid & 7;        // 0..7
  f32x4 acc[4][4] = {};

  const int nsteps = K >> 6;
  for (int s = 0; s < nsteps; ++s) {
    const int k0 = s * 64;
#pragma unroll
    for (int p = 0; p < 2; ++p) {
      const int row = p * 64 + rr;
      const int gm = m0 + row;
      bf16x8 av = {0, 0, 0, 0, 0, 0, 0, 0};
      if (gm < M) av = *(const bf16x8*)(A + (size_t)gm * K + k0 + cc * 8);
      const uint32_t off = (uint32_t)((row * 128 + cc * 16) ^ ((row & 7) << 4));
      *(bf16x8*)((char*)lA + off) = av;
    }
#pragma unroll
    for (int p = 0; p < 4; ++p) {
      const int row = p * 64 + rr;
      bf16x8 bv = *(const bf16x8*)(B + (size_t)row * K + k0 + cc * 8);
      const uint32_t off = (uint32_t)((row * 128 + cc * 16) ^ ((row & 7) << 4));
      *(bf16x8*)((char*)lB + off) = bv;
    }
    __syncthreads();
#pragma unroll
    for (int kk = 0; kk < 2; ++kk) {
      bf16x8 ah[4];
#pragma unroll
      for (int i = 0; i < 4; ++i) {
        const int arow = wm + i * 16 + (lane & 15);
        const uint32_t ao =
            (uint32_t)((arow * 128 + kk * 64 + ((lane >> 4) * 16)) ^ ((arow & 7) << 4));
        ah[i] = *(const bf16x8*)((const char*)lA + ao);
      }
#pragma unroll
      for (int j = 0; j < 4; ++j) {
        const int brow = wn + j * 16 + (lane & 15);
        const uint32_t bo =
            (uint32_t)((brow * 128 + kk * 64 + ((lane >> 4) * 16)) ^ ((brow & 7) << 4));
        const bf16x8 bv = *(const bf16x8*)((const char*)lB + bo);
#pragma unroll
        for (int i = 0; i < 4; ++i)
          acc[i][j] = __builtin_amdgcn_mfma_f32_16x16x32_bf16(ah[i], bv, acc[i][j], 0, 0, 0);
      }
    }
    __syncthreads();
  }

  float bi[4];
#pragma unroll
  for (int j = 0; j < 4; ++j) bi[j] = bias[wn + j * 16 + (lane & 15)];

  if (LN) {
    float gv[4], bv[4];
#pragma unroll
    for (int j = 0; j < 4; ++j) {
      gv[j] = g[wn + j * 16 + (lane & 15)];
      bv[j] = b_[wn + j * 16 + (lane & 15)];
    }
#pragma unroll
    for (int i = 0; i < 4; ++i) {
#pragma unroll
      for (int r = 0; r < 4; ++r) {
        float s1 = 0.f, s2 = 0.f;
#pragma unroll
        for (int j = 0; j < 4; ++j) {
          float v = acc[i][j][r] + bi[j];
          acc[i][j][r] = v;
          s1 += v;
          s2 += v * v;
        }
#pragma unroll
        for (int d = 1; d < 16; d <<= 1) {
          s1 += __shfl_xor(s1, d);
          s2 += __shfl_xor(s2, d);
        }
        if ((lane & 15) == 0) {
          const int rl = wm + i * 16 + ((lane >> 4) << 2) + r;
          sstat[0][w & 3][rl] = s1;
          sstat[1][w & 3][rl] = s2;
        }
      }
    }
    __syncthreads();
#pragma unroll
    for (int i = 0; i < 4; ++i) {
#pragma unroll
      for (int r = 0; r < 4; ++r) {
        const int rl = wm + i * 16 + ((lane >> 4) << 2) + r;
        const float s1 = sstat[0][0][rl] + sstat[0][1][rl] + sstat[0][2][rl] + sstat[0][3][rl];
        const float s2 = sstat[1][0][rl] + sstat[1][1][rl] + sstat[1][2][rl] + sstat[1][3][rl];
        const float mu = s1 * (1.f / 256.f);
        const float var = s2 * (1.f / 256.f) - mu * mu;
        const float rs = rsqrtf(var + 1e-5f);
        const int gm = m0 + rl;
        if (gm < M) {
          const size_t base = (size_t)gm * 256 + wn + (lane & 15);
#pragma unroll
          for (int j = 0; j < 4; ++j)
            C[base + j * 16] = f2bf((acc[i][j][r] - mu) * rs * gv[j] + bv[j]);
        }
      }
    }
  } else {
#pragma unroll
    for (int i = 0; i < 4; ++i) {
      const int gm0 = m0 + wm + i * 16 + ((lane >> 4) << 2);
#pragma unroll
      for (int r = 0; r < 4; ++r) {
        const int gm = gm0 + r;
        if (gm < M) {
          const size_t base = (size_t)gm * 256 + wn + (lane & 15);
#pragma unroll
          for (int j = 0; j < 4; ++j) {
            float v = acc[i][j][r] + bi[j];
            if (ADDZ) v += bf2f(Z[base + j * 16]);
            if (RELU) v = fmaxf(v, 0.f);
            C[base + j * 16] = f2bf(v);
          }
        }
      }
    }
  }
}

// ---------------------------------------------------------------------------
// Fold: outp (+)= sum_{k<P} betas[l0+k] * bf2f(zbase[k][i]); 8 elems/thread.
// ---------------------------------------------------------------------------
template <int WRITE>
__global__ __launch_bounds__(256) void fold_kernel(
    const ushort* __restrict__ zbase, size_t ZS, const float* __restrict__ betas,
    int l0, int P, float* __restrict__ outp, int total8) {
  const int i = blockIdx.x * 256 + threadIdx.x;
  if (i >= total8) return;
  float a[8] = {};
  for (int k = 0; k < P; ++k) {
    const float bl = betas[l0 + k];
    const uint4 u = ((const uint4*)(zbase + k * ZS))[i];
    const uint32_t ww[4] = {u.x, u.y, u.z, u.w};
#pragma unroll
    for (int q = 0; q < 4; ++q) {
      union { uint32_t u; float f; } lo, hi;
      lo.u = ww[q] << 16;
      hi.u = ww[q] & 0xffff0000u;
      a[2 * q] += bl * lo.f;
      a[2 * q + 1] += bl * hi.f;
    }
  }
  f32x4 o0 = {a[0], a[1], a[2], a[3]};
  f32x4 o1 = {a[4], a[5], a[6], a[7]};
  if (WRITE) {
    ((f32x4*)outp)[(size_t)i * 2] = o0;
    ((f32x4*)outp)[(size_t)i * 2 + 1] = o1;
  } else {
    f32x4 p0 = ((f32x4*)outp)[(size_t)i * 2];
    f32x4 p1 = ((f32x4*)outp)[(size_t)i * 2 + 1];
    ((f32x4*)outp)[(size_t)i * 2] = p0 + o0;
    ((f32x4*)outp)[(size_t)i * 2 + 1] = p1 + o1;
  }
}

// ---------------------------------------------------------------------------
// CSR build (parallel scan)
// ---------------------------------------------------------------------------
__global__ void count_kernel(const int* __restrict__ dstv, int* __restrict__ deg, int E) {
  int i = blockIdx.x * 256 + threadIdx.x;
  if (i < E) atomicAdd(&deg[dstv[i]], 1);
}

__global__ void scanA_kernel(const int* __restrict__ deg, int* __restrict__ excl,
                             int* __restrict__ bsum, int n) {
  __shared__ int sm[256];
  const int i = blockIdx.x * 256 + threadIdx.x;
  const int v = (i < n) ? deg[i] : 0;
  sm[threadIdx.x] = v;
  __syncthreads();
  for (int off = 1; off < 256; off <<= 1) {
    int t = (threadIdx.x >= off) ? sm[threadIdx.x - off] : 0;
    __syncthreads();
    sm[threadIdx.x] += t;
    __syncthreads();
  }
  if (i < n) excl[i] = sm[threadIdx.x] - v;
  if (threadIdx.x == 255) bsum[blockIdx.x] = sm[255];
}

__global__ void scanB_kernel(const int* __restrict__ bsum, int* __restrict__ boff, int nb) {
  __shared__ int sm[256];
  const int v = (threadIdx.x < nb) ? bsum[threadIdx.x] : 0;
  sm[threadIdx.x] = v;
  __syncthreads();
  for (int off = 1; off < 256; off <<= 1) {
    int t = (threadIdx.x >= off) ? sm[threadIdx.x - off] : 0;
    __syncthreads();
    sm[threadIdx.x] += t;
    __syncthreads();
  }
  if (threadIdx.x < nb) boff[threadIdx.x] = sm[threadIdx.x] - v;
}

__global__ void scanC_kernel(const int* __restrict__ deg, const int* __restrict__ excl,
                             const int* __restrict__ boff, int* __restrict__ rowptr,
                             int* __restrict__ fillptr, float* __restrict__ invc,
                             int n, int E) {
  const int i = blockIdx.x * 256 + threadIdx.x;
  if (i < n) {
    const int r = excl[i] + boff[blockIdx.x];
    rowptr[i] = r;
    fillptr[i] = r;
    invc[i] = 1.0f / (float)(deg[i] + 1);
  }
  if (i == 0) rowptr[n] = E;
}

__global__ void fill_kernel(const int* __restrict__ srcv, const int* __restrict__ dstv,
                            int* __restrict__ fillptr, int* __restrict__ colv, int E) {
  int i = blockIdx.x * 256 + threadIdx.x;
  if (i < E) {
    int p = atomicAdd(&fillptr[dstv[i]], 1);
    colv[p] = srcv[i];
  }
}

// ---------------------------------------------------------------------------
// 128-d aggregation over bf16 T -> bf16 s, unroll x4 for MLP.
// ---------------------------------------------------------------------------
__global__ __launch_bounds__(256) void agg128_kernel(
    const uint32_t* __restrict__ T, const int* __restrict__ rowptr,
    const int* __restrict__ colv, const float* __restrict__ invc,
    uint32_t* __restrict__ sout, int n) {
  const int node = blockIdx.x * 4 + (threadIdx.x >> 6);
  if (node >= n) return;
  const int lane = threadIdx.x & 63;
  auto up0 = [](uint32_t u) {
    union { uint32_t u; float f; } a; a.u = u << 16; return a.f;
  };
  auto up1 = [](uint32_t u) {
    union { uint32_t u; float f; } a; a.u = u & 0xffff0000u; return a.f;
  };
  const uint32_t self = T[(size_t)node * 64 + lane];
  float a0 = up0(self), a1 = up1(self);
  float b0 = 0.f, b1 = 0.f, c0 = 0.f, c1 = 0.f, d0 = 0.f, d1 = 0.f;
  const int s = rowptr[node];
  const int e = rowptr[node + 1];
  int i = s;
  for (; i + 3 < e; i += 4) {
    const int s0 = colv[i], s1 = colv[i + 1], s2 = colv[i + 2], s3 = colv[i + 3];
    const uint32_t u0 = T[(size_t)s0 * 64 + lane];
    const uint32_t u1 = T[(size_t)s1 * 64 + lane];
    const uint32_t u2 = T[(size_t)s2 * 64 + lane];
    const uint32_t u3 = T[(size_t)s3 * 64 + lane];
    a0 += up0(u0); a1 += up1(u0);
    b0 += up0(u1); b1 += up1(u1);
    c0 += up0(u2); c1 += up1(u2);
    d0 += up0(u3); d1 += up1(u3);
  }
  for (; i < e; ++i) {
    const uint32_t u0 = T[(size_t)colv[i] * 64 + lane];
    a0 += up0(u0); a1 += up1(u0);
  }
  const float ic = invc[node];
  const float r0 = (a0 + b0 + c0 + d0) * ic;
  const float r1 = (a1 + b1 + c1 + d1) * ic;
  sout[(size_t)node * 64 + lane] = (uint32_t)f2bf(r0) | ((uint32_t)f2bf(r1) << 16);
}

__global__ void beta_kernel(const float* __restrict__ beta, float* __restrict__ betas) {
  if (threadIdx.x == 0) {
    float mx = beta[0];
    for (int i = 1; i < NLAYER + 1; ++i) mx = fmaxf(mx, beta[i]);
    float e[NLAYER + 1];
    float s = 0.f;
    for (int i = 0; i < NLAYER + 1; ++i) {
      e[i] = expf(beta[i] - mx);
      s += e[i];
    }
    const float inv = 1.f / s;
    for (int i = 0; i < NLAYER + 1; ++i) betas[i] = e[i] * inv;
  }
}

// W[K][N] f32 -> Wt[N][K] bf16
__global__ void wconv_kernel(const float* __restrict__ W, ushort* __restrict__ Wt,
                             int K, int Nn) {
  const size_t matoff = (size_t)blockIdx.z * K * Nn;
  const int o = blockIdx.x * 256 + threadIdx.x;
  if (o >= K * Nn) return;
  const int nn = o / K;
  const int kk = o - nn * K;
  Wt[matoff + o] = f2bf(W[matoff + (size_t)kk * Nn + nn]);
}

// x f32 -> bf16, 8/thread
__global__ void xcast_kernel(const float* __restrict__ x, ushort* __restrict__ xb, int n8) {
  const int i = blockIdx.x * 256 + threadIdx.x;
  if (i >= n8) return;
  const f32x4 v0 = ((const f32x4*)x)[(size_t)i * 2];
  const f32x4 v1 = ((const f32x4*)x)[(size_t)i * 2 + 1];
  bf16x8 o;
#pragma unroll
  for (int q = 0; q < 4; ++q) {
    o[q] = (short)f2bf(v0[q]);
    o[q + 4] = (short)f2bf(v1[q]);
  }
  *(bf16x8*)(xb + (size_t)i * 8) = o;
}

// ---------------------------------------------------------------------------
extern "C" void kernel_launch(void* const* d_in, const int* in_sizes, int n_in,
                              void* d_out, int out_size, void* d_ws, size_t ws_size,
                              hipStream_t stream) {
  const float* x = (const float*)d_in[0];
  const int* eidx = (const int*)d_in[1];
  const float* Win = (const float*)d_in[2];
  const float* bin_ = (const float*)d_in[3];
  const float* W1 = (const float*)d_in[4];
  const float* b1 = (const float*)d_in[5];
  const float* W2 = (const float*)d_in[6];
  const float* b2 = (const float*)d_in[7];
  const float* U1 = (const float*)d_in[8];
  const float* c1 = (const float*)d_in[9];
  const float* U2 = (const float*)d_in[10];
  const float* c2 = (const float*)d_in[11];
  const float* ln_g = (const float*)d_in[12];
  const float* ln_b = (const float*)d_in[13];
  const float* beta = (const float*)d_in[14];
  float* outp = (float*)d_out;

  const int Nn = in_sizes[0] / 128;  // 50000
  const int E = in_sizes[1] / 2;     // 800000
  const int* srcv = eidx;
  const int* dstv = eidx + E;

  char* p = (char*)d_ws;
  auto alloc = [&](size_t bytes) {
    char* r = p;
    p += (bytes + 255) & ~(size_t)255;
    return r;
  };
  ushort* hbuf = (ushort*)alloc((size_t)Nn * HIDC * 2);  // h bf16
  ushort* TSO = (ushort*)alloc((size_t)Nn * HIDC * 2);   // T|s (each Nn x 128), or O
  ushort* xbf = (ushort*)alloc((size_t)Nn * 128 * 2);    // x bf16
  ushort* WinT = (ushort*)alloc(128 * 256 * 2);
  ushort* W1T = (ushort*)alloc((size_t)NLAYER * 256 * 128 * 2);
  ushort* W2T = (ushort*)alloc((size_t)NLAYER * 128 * 256 * 2);
  ushort* U1T = (ushort*)alloc((size_t)NLAYER * 256 * 256 * 2);
  ushort* U2T = (ushort*)alloc((size_t)NLAYER * 256 * 256 * 2);
  int* deg = (int*)alloc((size_t)Nn * 4);
  int* rowptr = (int*)alloc((size_t)(Nn + 1) * 4);
  int* fillptr = (int*)alloc((size_t)Nn * 4);
  float* invc = (float*)alloc((size_t)Nn * 4);
  int* colv = (int*)alloc((size_t)E * 4);
  int* excl = (int*)alloc((size_t)Nn * 4);
  int* bsum = (int*)alloc(256 * 4);
  int* boff = (int*)alloc(256 * 4);
  float* betas = (float*)alloc(64);

  // z-history slots: as many as fit (G in [2, 11])
  const size_t ZS = (size_t)Nn * HIDC;        // elems per slot
  const size_t slotB = ZS * 2;                // 25.6 MB
  const size_t used = (size_t)(p - (char*)d_ws);
  int G = 2;
  if (ws_size > used + 4096) {
    size_t fit = (ws_size - used - 4096) / (slotB + 256);
    G = (int)(fit < 2 ? 2 : (fit > NLAYER + 1 ? NLAYER + 1 : fit));
  }
  ushort* zbase = (ushort*)alloc((size_t)G * slotB);

  ushort* T128 = TSO;                       // [Nn x 128]
  ushort* s128 = TSO + (size_t)Nn * MSGC;   // [Nn x 128]
  ushort* Obuf = TSO;                       // [Nn x 256]

  const int nscan = (Nn + 255) / 256;
  const int mb128 = (Nn + 127) / 128;
  const int nwave = (Nn + 3) / 4;
  const int total8 = (Nn * HIDC) / 8;

  hipMemsetAsync(deg, 0, (size_t)Nn * 4, stream);
  count_kernel<<<(E + 255) / 256, 256, 0, stream>>>(dstv, deg, E);
  scanA_kernel<<<nscan, 256, 0, stream>>>(deg, excl, bsum, Nn);
  scanB_kernel<<<1, 256, 0, stream>>>(bsum, boff, nscan);
  scanC_kernel<<<nscan, 256, 0, stream>>>(deg, excl, boff, rowptr, fillptr, invc, Nn, E);
  fill_kernel<<<(E + 255) / 256, 256, 0, stream>>>(srcv, dstv, fillptr, colv, E);
  beta_kernel<<<1, 64, 0, stream>>>(beta, betas);
  xcast_kernel<<<(Nn * 16 + 255) / 256, 256, 0, stream>>>(x, xbf, Nn * 16);
  wconv_kernel<<<dim3(128, 1, 1), 256, 0, stream>>>(Win, WinT, 128, 256);
  wconv_kernel<<<dim3(128, 1, NLAYER), 256, 0, stream>>>(W1, W1T, 256, 128);
  wconv_kernel<<<dim3(128, 1, NLAYER), 256, 0, stream>>>(W2, W2T, 128, 256);
  wconv_kernel<<<dim3(256, 1, NLAYER), 256, 0, stream>>>(U1, U1T, 256, 256);
  wconv_kernel<<<dim3(256, 1, NLAYER), 256, 0, stream>>>(U2, U2T, 256, 256);

  // fold bookkeeping
  int pend = 0, l0 = 0;
  bool first = true;
  auto flush = [&]() {
    if (pend > 0) {
      if (first)
        fold_kernel<1><<<(total8 + 255) / 256, 256, 0, stream>>>(zbase, ZS, betas, l0,
                                                                 pend, outp, total8);
      else
        fold_kernel<0><<<(total8 + 255) / 256, 256, 0, stream>>>(zbase, ZS, betas, l0,
                                                                 pend, outp, total8);
      first = false;
      l0 += pend;
      pend = 0;
    }
  };

  // z0 = x @ Win + bin -> slot 0
  ushort* zcur = zbase;
  gemm_big<0, 0, 0><<<mb128, 512, 0, stream>>>(xbf, WinT, bin_, nullptr, zcur, nullptr,
                                               nullptr, Nn, 128);
  pend = 1;

  for (int l = 0; l < NLAYER; ++l) {
    // T = bf16(relu(z @ W1 + b1))
    gemm_w1<<<mb128, 256, 0, stream>>>(zcur, W1T + (size_t)l * 256 * 128, b1 + l * 128,
                                       T128, Nn);
    // s = bf16(segmean(T))
    agg128_kernel<<<nwave, 256, 0, stream>>>((const uint32_t*)T128, rowptr, colv, invc,
                                             (uint32_t*)s128, Nn);
    // h = bf16(z + s @ W2 + b2)
    gemm_big<0, 1, 0><<<mb128, 512, 0, stream>>>(s128, W2T + (size_t)l * 128 * 256,
                                                 b2 + l * 256, zcur, hbuf, nullptr,
                                                 nullptr, Nn, 128);
    // O = bf16(relu(h @ U1 + c1))
    gemm_big<1, 0, 0><<<mb128, 512, 0, stream>>>(hbuf, U1T + (size_t)l * 256 * 256,
                                                 c1 + l * 256, nullptr, Obuf, nullptr,
                                                 nullptr, Nn, 256);
    // fold if all slots full (zcur stays readable; its slot reused G layers later)
    if (pend == G) flush();
    // z_{l+1} = bf16(LN(O @ U2 + c2)*g + b) -> next slot
    ushort* znext = zbase + (size_t)pend * slotB / 2;
    gemm_big<0, 0, 1><<<mb128, 512, 0, stream>>>(Obuf, U2T + (size_t)l * 256 * 256,
                                                 c2 + l * 256, nullptr, znext,
                                                 ln_g + l * 256, ln_b + l * 256, Nn, 256);
    zcur = znext;
    pend++;
  }
  flush();
}